// Round 5
// baseline (6658.824 us; speedup 1.0000x reference)
//
#include <hip/hip_runtime.h>

typedef unsigned short ushort;
typedef unsigned int uint;
typedef __attribute__((ext_vector_type(8))) short short8;
typedef __attribute__((ext_vector_type(4))) float f32x4;
typedef __attribute__((ext_vector_type(4))) uint u32x4;

#define DEVI __device__ __forceinline__

#define B_ 32
#define SIN_ 128
#define SOUT_ 32
#define Y_ 256
#define H_ 512
#define E_ 256
#define TH_ 1536

DEVI float b2f(ushort u){ return __uint_as_float(((uint)u)<<16); }
DEVI ushort f2b(float f){ uint x = __float_as_uint(f); return (ushort)((x + 0x7FFFu + ((x>>16)&1u)) >> 16); }
DEVI float sigf(float x){ return 1.f/(1.f+__expf(-x)); }
DEVI float tanh_fast(float x){ return 2.f/(1.f+__expf(-2.f*x)) - 1.f; }
DEVI float splus(float x){ return fmaxf(x,0.f) + log1pf(__expf(-fabsf(x))); }
DEVI short8 cvt8(u32x4 v){ return __builtin_bit_cast(short8, v); }

// sc0 sc1 = coherent through Infinity Cache (cross-XCD visible without fences)
DEVI uint ld_flag(const uint* p){
  uint r;
  asm volatile("global_load_dword %0, %1, off sc0 sc1\n\ts_waitcnt vmcnt(0)"
               : "=v"(r) : "v"(p) : "memory");
  return r;
}
DEVI void st_flag(uint* p, uint v){
  asm volatile("global_store_dword %0, %1, off sc0 sc1" :: "v"(p), "v"(v) : "memory");
}
DEVI void st_h16(ushort* p, uint v){
  asm volatile("global_store_short %0, %1, off sc0 sc1" :: "v"(p), "v"(v) : "memory");
}
DEVI void stf_sc1(float* p, float v){
  asm volatile("global_store_dword %0, %1, off sc0 sc1" :: "v"(p), "v"(__float_as_uint(v)) : "memory");
}
// 16 contiguous floats, coherent
DEVI void ld16_sc1(const float* p, float* o){
  u32x4 r0,r1,r2,r3;
  asm volatile("global_load_dwordx4 %0, %4, off sc0 sc1\n\t"
               "global_load_dwordx4 %1, %4, off offset:16 sc0 sc1\n\t"
               "global_load_dwordx4 %2, %4, off offset:32 sc0 sc1\n\t"
               "global_load_dwordx4 %3, %4, off offset:48 sc0 sc1\n\t"
               "s_waitcnt vmcnt(0)"
               : "=&v"(r0),"=&v"(r1),"=&v"(r2),"=&v"(r3) : "v"(p) : "memory");
  *(u32x4*)(o) = r0; *(u32x4*)(o+4) = r1; *(u32x4*)(o+8) = r2; *(u32x4*)(o+12) = r3;
}

// ---------------- init / reductions ----------------
__global__ void k_init(float* acc){ if (threadIdx.x < 4) acc[threadIdx.x] = 0.f; }

__global__ void k_wsfail(float* out){ out[0]=1.2345e8f; out[1]=2.3456e8f; out[2]=3.4567e8f; }

__global__ void k_init_enc(uint* __restrict__ flags, ushort* __restrict__ hG)
{
  const int id = blockIdx.x*256 + threadIdx.x;
  if (id < 256) flags[id] = 0u;
  // hG: 2 buf * 2 dir * 32 * 512 ushorts = 65536 ushorts = 8192 uint4
  if (id < 8192) ((uint4*)hG)[id] = make_uint4(0,0,0,0);
}

__global__ __launch_bounds__(256) void k_ysum(const float* __restrict__ yv, float* __restrict__ acc)
{
  __shared__ float red[256];
  float s = 0.f;
  for (long i = (long)blockIdx.x*256 + threadIdx.x; i < (long)B_*SOUT_*Y_; i += (long)gridDim.x*256) s += yv[i];
  red[threadIdx.x] = s; __syncthreads();
  for (int o=128;o;o>>=1){ if ((int)threadIdx.x<o) red[threadIdx.x] += red[threadIdx.x+o]; __syncthreads(); }
  if (threadIdx.x==0) atomicAdd(acc+2, red[0]);
}

// ---------------- embedding / lookup ----------------
__global__ void k_lookup(const int* __restrict__ x, const int* __restrict__ akey,
                         const int* __restrict__ atype, const int* __restrict__ croom,
                         const float* __restrict__ yv,
                         const float* __restrict__ emb, const float* __restrict__ attab,
                         ushort* __restrict__ embxs, ushort* __restrict__ aemb,
                         ushort* __restrict__ aembT, float* __restrict__ avec,
                         ushort* __restrict__ acat, ushort* __restrict__ yprev)
{
  const long N1 = (long)SIN_*B_*E_;
  const long N2 = (long)Y_*E_;
  const long N3 = (long)Y_*32;
  const long N4 = (long)SOUT_*B_*E_;
  const long N5 = (long)SOUT_*B_*Y_;
  for (long i = (long)blockIdx.x*blockDim.x + threadIdx.x; i < N1+N2+N3+N4+N5; i += (long)gridDim.x*blockDim.x){
    long id = i;
    if (id < N1){
      int e = id & 255; long sb = id >> 8; int bb = (int)(sb & 31); int s = (int)(sb >> 5);
      embxs[id] = f2b(emb[(size_t)x[bb*SIN_ + s]*E_ + e]);
    } else if ((id -= N1) < N2){
      int e = (int)(id & 255), yy = (int)(id >> 8);
      ushort v = f2b(emb[(size_t)akey[yy]*E_ + e]);
      aemb[yy*E_ + e] = v;
      aembT[e*Y_ + yy] = v;
    } else if ((id -= N2) < N3){
      int a = (int)(id & 31), yy = (int)(id >> 5);
      avec[yy*32 + a] = attab[atype[yy]*32 + a];
    } else if ((id -= N3) < N4){
      int e = (int)(id & 255); long tb = id >> 8; int bb = (int)(tb & 31); int t = (int)(tb >> 5);
      acat[(size_t)tb*512 + e] = f2b(emb[(size_t)croom[bb*SOUT_ + t]*E_ + e]);
    } else { id -= N4;
      int yy = (int)(id & 255); long tb = id >> 8; int bb = (int)(tb & 31); int t = (int)(tb >> 5);
      yprev[id] = (t == 0) ? (ushort)0 : f2b(yv[((size_t)bb*SOUT_ + (t-1))*Y_ + yy]);
    }
  }
}

// all f32->bf16 weight conversions in one kernel
__global__ __launch_bounds__(256)
void k_convall(const float* __restrict__ eWihF, const float* __restrict__ eWihB,
               const float* __restrict__ transW, const float* __restrict__ dWih,
               const float* __restrict__ cW1, const float* __restrict__ dWhh,
               ushort* __restrict__ WihFb, ushort* __restrict__ WihBb,
               ushort* __restrict__ Wtrb, ushort* __restrict__ Wattb,
               ushort* __restrict__ Wcat2b, ushort* __restrict__ W1attb,
               ushort* __restrict__ Wdecb, ushort* __restrict__ Wchk2b)
{
  const long N1 = 393216;
  const long N2 = 393216;
  const long N3 = 262144;
  const long N4 = 1572864;
  const long N5 = 393216;
  const long N6 = 393216;
  const long N7 = 524288;
  const long N8 = 786432;
  const long N9 = 262144;
  const long NT = N1+N2+N3+N4+N5+N6+N7+N8+N9;
  for (long i = (long)blockIdx.x*256 + threadIdx.x; i < NT; i += (long)gridDim.x*256){
    long id = i;
    if (id < N1){ WihFb[id] = f2b(eWihF[id]); }
    else if ((id -= N1) < N2){ WihBb[id] = f2b(eWihB[id]); }
    else if ((id -= N2) < N3){ Wtrb[id] = f2b(transW[id]); }
    else if ((id -= N3) < N4){
      const long r = id>>10, c = id&1023;
      Wattb[id] = f2b(dWih[r*1569 + c]);
    }
    else if ((id -= N4) < N5){
      const long r = id>>8, c = id&255;
      Wcat2b[r*512 + c] = f2b(dWih[r*1569 + 1025 + c]);
    }
    else if ((id -= N5) < N6){
      const long r = id>>8, c = id&255;
      Wcat2b[r*512 + 256 + c] = f2b(dWih[r*1569 + 1313 + c]);
    }
    else if ((id -= N6) < N7){
      const long r = id>>10, c = id&1023;
      W1attb[id] = f2b(cW1[r*1568 + c]);
    }
    else if ((id -= N7) < N8){ Wdecb[id] = f2b(dWhh[id]); }
    else { id -= N8;
      const long r = id>>9, c = id&511;
      Wchk2b[id] = f2b(cW1[r*1568 + 1056 + c]);
    }
  }
}

// add_y, addc_y, wchk, dbhh_rz
__global__ void k_prep2(const float* __restrict__ avec, const float* __restrict__ decWih,
                        const float* __restrict__ dbih, const float* __restrict__ cW1,
                        const float* __restrict__ cb1, const float* __restrict__ dbhh,
                        float* __restrict__ addy, float* __restrict__ addcy,
                        float* __restrict__ wchk, float* __restrict__ dbhhrz)
{
  const long NA = (long)Y_*TH_;
  const long NB = (long)Y_*H_;
  for (long i = (long)blockIdx.x*blockDim.x + threadIdx.x; i < NA+NB+TH_+TH_; i += (long)gridDim.x*blockDim.x){
    long id = i;
    if (id < NA){
      int n = (int)(id % TH_), yy = (int)(id / TH_);
      float s = dbih[n];
      const float* wr = decWih + (size_t)n*1569 + 1281;
      const float* av = avec + yy*32;
      #pragma unroll
      for (int a=0;a<32;++a) s += av[a]*wr[a];
      addy[id] = s;
    } else if ((id -= NA) < NB){
      int n = (int)(id & 511), yy = (int)(id >> 9);
      float s = cb1[n];
      const float* wr = cW1 + (size_t)n*1568 + 1024;
      const float* av = avec + yy*32;
      #pragma unroll
      for (int a=0;a<32;++a) s += av[a]*wr[a];
      addcy[id] = s;
    } else if ((id -= NB) < TH_){
      wchk[id] = decWih[(size_t)id*1569 + 1024];
    } else { id -= TH_;
      dbhhrz[id] = (id < 1024) ? dbhh[id] : 0.f;
    }
  }
}

// ---------------- bf16 NT GEMM: C[M,N] = A[M,K] @ W[N,K]^T  (MFMA 16x16x32) ----------------
#define GF_BIAS 1
#define GF_TANH 2
#define GF_WF32 4
#define GF_WBF16 8
#define GF_ADDY 32
#define GF_ESUM 128

template<int FLAGS>
__global__ __launch_bounds__(256)
void gemm_nt(const ushort* __restrict__ A, const ushort* __restrict__ W,
             const float* __restrict__ bias,
             const float* __restrict__ addy, int lday,
             float* __restrict__ Cf, ushort* __restrict__ Cb, int ldC,
             int K, int ldA, int ldW, int n0,
             long zA, long zW, long zC,
             const ushort* __restrict__ chkbase)
{
  const int z = blockIdx.z;
  A += (long)z*zA; W += (long)z*zW;
  const int bn = n0 + (blockIdx.x<<7);
  const int bm = (blockIdx.y<<7);
  const int tid = threadIdx.x;
  const int w = tid>>6, lane = tid&63;
  const int wm = (w>>1)<<6, wn = (w&1)<<6;
  const int rs = tid>>1;
  const int kh = (tid&1)<<5;
  __shared__ ushort lsA[8192];
  __shared__ ushort lsB[8192];
  f32x4 acc[4][4];
  #pragma unroll
  for (int i=0;i<4;++i)
    #pragma unroll
    for (int jj=0;jj<4;++jj) acc[i][jj] = 0.f;

  const ushort* pa = A + (size_t)(bm+rs)*ldA + kh;
  const ushort* pb = W + (size_t)(bn+rs)*ldW + kh;
  uint4 va[4], vb[4];
  #pragma unroll
  for (int i=0;i<4;++i){ va[i] = *(const uint4*)(pa + i*8); vb[i] = *(const uint4*)(pb + i*8); }
  const int nkt = K>>6;
  for (int kt=0; kt<nkt; ++kt){
    __syncthreads();
    #pragma unroll
    for (int i=0;i<4;++i){
      const int c = ((tid&1)<<2) + i;
      *(uint4*)&lsA[(size_t)((c<<7) + rs)<<3] = va[i];
      *(uint4*)&lsB[(size_t)((c<<7) + rs)<<3] = vb[i];
    }
    __syncthreads();
    if (kt+1 < nkt){
      const ushort* qa = pa + (size_t)(kt+1)*64;
      const ushort* qb = pb + (size_t)(kt+1)*64;
      #pragma unroll
      for (int i=0;i<4;++i){ va[i] = *(const uint4*)(qa + i*8); vb[i] = *(const uint4*)(qb + i*8); }
    }
    #pragma unroll
    for (int ks=0;ks<2;++ks){
      const int ch = (ks<<2) + (lane>>4);
      short8 af[4], bf[4];
      #pragma unroll
      for (int mi=0;mi<4;++mi) af[mi] = *(const short8*)&lsA[(size_t)((ch<<7) + wm + (mi<<4) + (lane&15))<<3];
      #pragma unroll
      for (int ni=0;ni<4;++ni) bf[ni] = *(const short8*)&lsB[(size_t)((ch<<7) + wn + (ni<<4) + (lane&15))<<3];
      #pragma unroll
      for (int mi=0;mi<4;++mi)
        #pragma unroll
        for (int ni=0;ni<4;++ni)
          acc[mi][ni] = __builtin_amdgcn_mfma_f32_16x16x32_bf16(af[mi], bf[ni], acc[mi][ni], 0,0,0);
    }
  }
  const long zc = (long)z*zC;
  #pragma unroll
  for (int mi=0;mi<4;++mi){
    #pragma unroll
    for (int ni=0;ni<4;++ni){
      const int col = bn + wn + (ni<<4) + (lane&15);
      const int row0 = bm + wm + (mi<<4) + ((lane>>4)<<2);
      float bv = 0.f;
      if (FLAGS & GF_BIAS) bv = bias[col];
      #pragma unroll
      for (int q=0;q<4;++q){
        const int row = row0 + q;
        float xv = acc[mi][ni][q] + bv;
        if (FLAGS & GF_ADDY) xv += addy[(size_t)(row&255)*lday + col];
        if (FLAGS & GF_TANH) xv = tanh_fast(xv);
        if (FLAGS & GF_ESUM) xv += b2f(chkbase[((size_t)(row&127)*32 + (row>>7))*256 + col]);
        if (FLAGS & GF_WF32)  Cf[zc + (size_t)row*ldC + col] = xv;
        if (FLAGS & GF_WBF16) Cb[zc + (size_t)row*ldC + col] = f2b(xv);
      }
    }
  }
}

// ---------------- persistent bi-GRU encoder (fence-free sc1 exchange, hi-only bf16 h) ----------------
__global__ __launch_bounds__(256,1)
void enc_persist(const float* __restrict__ Wf, const float* __restrict__ Wb,
                 const float* __restrict__ bhf, const float* __restrict__ bhb,
                 const ushort* __restrict__ gif, const ushort* __restrict__ gib,
                 ushort* __restrict__ hG, uint* __restrict__ flags,
                 ushort* __restrict__ encout, ushort* __restrict__ encoutT,
                 float* __restrict__ hTf, float* __restrict__ hTb)
{
  const int g = blockIdx.x;
  const int dir = g >> 5;
  const int j0 = (g & 31) << 4;
  const int tid = threadIdx.x;
  const int w = tid >> 6, lane = tid & 63;
  const int mi = w & 1, kh = w >> 1;
  const int l15 = lane & 15, l4 = lane >> 4;
  const int brow0 = mi*16 + l4*4;

  const float* W = dir ? Wb : Wf;
  const float* bh = dir ? bhb : bhf;
  const ushort* gi = dir ? gib : gif;

  __shared__ __align__(16) float cred[2][3][256];
  __shared__ float bhl[48];

  short8 bw[3][8];
  {
    const int kbase = kh*256 + l4*8;
    #pragma unroll
    for (int ni=0; ni<3; ++ni){
      const float* wr = W + (size_t)(ni*512 + j0 + l15)*512 + kbase;
      #pragma unroll
      for (int ks=0; ks<8; ++ks){
        const float4 f0 = *(const float4*)(wr + ks*32);
        const float4 f1 = *(const float4*)(wr + ks*32 + 4);
        short8 v;
        v[0]=(short)f2b(f0.x); v[1]=(short)f2b(f0.y); v[2]=(short)f2b(f0.z); v[3]=(short)f2b(f0.w);
        v[4]=(short)f2b(f1.x); v[5]=(short)f2b(f1.y); v[6]=(short)f2b(f1.z); v[7]=(short)f2b(f1.w);
        bw[ni][ks] = v;
      }
    }
  }
  if (tid < 48) bhl[tid] = bh[(tid>>4)*512 + j0 + (tid&15)];
  __syncthreads();

  float bh0r=0.f, bh1r=0.f, bh2r=0.f;
  if (kh==0){ bh0r = bhl[l15]; bh1r = bhl[16+l15]; bh2r = bhl[32+l15]; }
  float holdr[4] = {0.f,0.f,0.f,0.f};
  uint* myflag = flags + dir*32 + (g&31);

  for (int t=0; t<128; ++t){
    const int tt = dir ? (127 - t) : t;
    // gi prefetch (independent of the flag wait)
    float giv0[4], giv1[4], giv2[4];
    if (kh==0){
      const ushort* girow = gi + ((size_t)tt*32 + brow0)*1536 + j0 + l15;
      #pragma unroll
      for (int q=0; q<4; ++q){
        giv0[q] = b2f(girow[q*1536]);
        giv1[q] = b2f(girow[q*1536 + 512]);
        giv2[q] = b2f(girow[q*1536 + 1024]);
      }
    }
    if (t){
      if ((tid>>6)==2 && (tid&63)<32){
        const uint* fp = flags + dir*32 + (tid&31);
        while (ld_flag(fp) < (uint)t) __builtin_amdgcn_s_sleep(2);
      }
      __syncthreads();
    }
    const ushort* hsrc = hG + ((size_t)((t&1)*2 + dir))*16384 + (size_t)(mi*16+l15)*512 + kh*256 + l4*8;
    u32x4 a0,a1,a2,a3,a4,a5,a6,a7;
    asm volatile(
      "global_load_dwordx4 %0, %8, off sc0 sc1\n\t"
      "global_load_dwordx4 %1, %8, off offset:64 sc0 sc1\n\t"
      "global_load_dwordx4 %2, %8, off offset:128 sc0 sc1\n\t"
      "global_load_dwordx4 %3, %8, off offset:192 sc0 sc1\n\t"
      "global_load_dwordx4 %4, %8, off offset:256 sc0 sc1\n\t"
      "global_load_dwordx4 %5, %8, off offset:320 sc0 sc1\n\t"
      "global_load_dwordx4 %6, %8, off offset:384 sc0 sc1\n\t"
      "global_load_dwordx4 %7, %8, off offset:448 sc0 sc1\n\t"
      "s_waitcnt vmcnt(0)"
      : "=&v"(a0),"=&v"(a1),"=&v"(a2),"=&v"(a3),"=&v"(a4),"=&v"(a5),"=&v"(a6),"=&v"(a7)
      : "v"(hsrc)
      : "memory");
    const short8 ah[8] = {cvt8(a0),cvt8(a1),cvt8(a2),cvt8(a3),cvt8(a4),cvt8(a5),cvt8(a6),cvt8(a7)};
    f32x4 acc[3]; acc[0]=0.f; acc[1]=0.f; acc[2]=0.f;
    #pragma unroll
    for (int ks=0; ks<8; ++ks){
      acc[0] = __builtin_amdgcn_mfma_f32_16x16x32_bf16(ah[ks], bw[0][ks], acc[0],0,0,0);
      acc[1] = __builtin_amdgcn_mfma_f32_16x16x32_bf16(ah[ks], bw[1][ks], acc[1],0,0,0);
      acc[2] = __builtin_amdgcn_mfma_f32_16x16x32_bf16(ah[ks], bw[2][ks], acc[2],0,0,0);
    }
    if (kh==1){
      #pragma unroll
      for (int ni=0; ni<3; ++ni) *(f32x4*)&cred[mi][ni][lane*4] = acc[ni];
    }
    __syncthreads();
    ushort hbs[4];
    if (kh==0){
      #pragma unroll
      for (int ni=0; ni<3; ++ni){
        const f32x4 o = *(const f32x4*)&cred[mi][ni][lane*4];
        acc[ni][0]+=o[0]; acc[ni][1]+=o[1]; acc[ni][2]+=o[2]; acc[ni][3]+=o[3];
      }
      ushort* dst = hG + ((size_t)(((t+1)&1)*2 + dir))*16384;
      #pragma unroll
      for (int q=0; q<4; ++q){
        const int b = brow0 + q;
        const float r  = sigf(giv0[q] + acc[0][q] + bh0r);
        const float zg = sigf(giv1[q] + acc[1][q] + bh1r);
        const float n  = tanh_fast(giv2[q] + r*(acc[2][q] + bh2r));
        const float h2 = (1.f - zg)*n + zg*holdr[q];
        holdr[q] = h2;
        const ushort hb = f2b(h2);
        hbs[q] = hb;
        if (t < 127) st_h16(dst + (size_t)b*512 + j0 + l15, (uint)hb);
      }
    }
    __syncthreads();   // drains kh==0 waves' sc1 h-stores before flag
    if (t < 127 && tid == 0) st_flag(myflag, (uint)(t+1));
    if (kh==0){
      #pragma unroll
      for (int q=0; q<4; ++q){
        const int b = brow0 + q;
        encout[((size_t)b*SIN_ + tt)*1024 + dir*H_ + j0 + l15] = hbs[q];
        encoutT[((size_t)b*1024 + dir*H_ + j0 + l15)*SIN_ + tt] = hbs[q];
      }
    }
  }
  if (kh==0){
    float* hT = dir ? hTb : hTf;
    #pragma unroll
    for (int q=0; q<4; ++q) hT[(size_t)(brow0+q)*H_ + j0 + l15] = holdr[q];
  }
}

// row softmax over SIN=128, one wave per row
__global__ __launch_bounds__(256) void k_softmax(const float* __restrict__ sc, ushort* __restrict__ al)
{
  const int row = blockIdx.x*4 + (threadIdx.x>>6);
  const int lane = threadIdx.x&63;
  const float* s = sc + (size_t)row*SIN_;
  const float2 v = *(const float2*)&s[lane*2];
  float m = fmaxf(v.x, v.y);
  #pragma unroll
  for (int o=1;o<64;o<<=1) m = fmaxf(m, __shfl_xor(m, o));
  const float e0 = __expf(v.x - m), e1 = __expf(v.y - m);
  float sum = e0 + e1;
  #pragma unroll
  for (int o=1;o<64;o<<=1) sum += __shfl_xor(sum, o);
  const float inv = 1.f/sum;
  ushort* a = al + (size_t)row*SIN_;
  const uint pkv = (uint)f2b(e0*inv) | ((uint)f2b(e1*inv)<<16);
  *(uint*)&a[lane*2] = pkv;
}

// h0_dec = tanh(hidden_cat @ merge_W^T + merge_b)
__global__ __launch_bounds__(512)
void k_merge(const float* __restrict__ hTf, const float* __restrict__ hTb,
             const float* __restrict__ mW, const float* __restrict__ mb,
             float* __restrict__ h0)
{
  const int b = blockIdx.x, j = threadIdx.x;
  __shared__ float hc[1024];
  for (int i=j; i<1024; i+=512){
    const int half = i >> 9, jj = i & 511;
    hc[i] = (b < 16) ? hTf[(size_t)(2*b + half)*H_ + jj] : hTb[(size_t)(2*(b-16) + half)*H_ + jj];
  }
  __syncthreads();
  float d = mb[j];
  const float* wr = mW + (size_t)j*1024;
  #pragma unroll 8
  for (int k=0;k<1024;k+=4){
    const float4 a = *(const float4*)&wr[k];
    const float4 hh = *(const float4*)&hc[k];
    d += a.x*hh.x + a.y*hh.y + a.z*hh.z + a.w*hh.w;
  }
  h0[(size_t)b*H_ + j] = tanh_fast(d);
}

__global__ void k_bcast(const float* __restrict__ h0, ushort* __restrict__ hb,
                        float* __restrict__ L0, float* __restrict__ L1, uint* __restrict__ counter)
{
  for (long i = (long)blockIdx.x*blockDim.x + threadIdx.x; i < (long)8192*H_; i += (long)gridDim.x*blockDim.x){
    const int jj = (int)(i & 511); const long row = i >> 9; const int bb = (int)(row >> 8);
    hb[i] = f2b(h0[(size_t)bb*H_ + jj]);
    if (i < 8192){ L0[i] = 0.f; L1[i] = 0.f; }
    if (i == 0) counter[0] = 0u;
  }
}

// ---------------- combined decoder step ----------------
// blocks 0..255: recurrent GEMM + gates + logit partials for step tstep (skip if tstep==32)
// blocks 256..319: chk-MLP for step tstep-1 (skip if tstep==0); last one computes both losses.
__global__ __launch_bounds__(512,1)
void dec_step(const ushort* __restrict__ hin, ushort* __restrict__ hout,
              const ushort* __restrict__ Wd, const ushort* __restrict__ gib,
              const float* __restrict__ sproj_t, const float* __restrict__ wchk,
              const float* __restrict__ dbhh, const float* __restrict__ checked,
              const float* __restrict__ decW,
              const ushort* __restrict__ Wchk2b, const ushort* __restrict__ chkbase,
              const float* __restrict__ cw2, const float* __restrict__ cb2v,
              const float* __restrict__ yv,
              float* __restrict__ logitsW, float* __restrict__ logitsR,
              float* __restrict__ chkdot, uint* __restrict__ counter,
              float* __restrict__ accv, int tstep)
{
  __shared__ __align__(16) ushort smem[36864];
  __shared__ uint slast;
  const int tid = threadIdx.x;

  if (blockIdx.x < 256){
    // ---------------- dec role ----------------
    if (tstep >= SOUT_) return;
    const int bx = blockIdx.x & 3;
    const int by = blockIdx.x >> 2;
    const int bm = by<<7;
    const int w = tid>>6, lane = tid&63;
    const int wrh = w>>2, wc = w&3;
    const int wm = wrh<<6;
    const int l15 = lane&15, l4 = lane>>4;
    ushort* lsA = smem;
    ushort* lsB = smem + 128*72;
    f32x4 acc[3][4][2];
    #pragma unroll
    for (int gg=0;gg<3;++gg)
      #pragma unroll
      for (int mi2=0;mi2<4;++mi2)
        #pragma unroll
        for (int ni2=0;ni2<2;++ni2) acc[gg][mi2][ni2] = 0.f;

    const int saRow0 = tid>>3, saK = (tid&7)<<3;
    uint4 va[2], vb[6];
    {
      #pragma unroll
      for (int i=0;i<2;++i){
        const int row = saRow0 + (i<<6);
        va[i] = *(const uint4*)&hin[(size_t)(bm+row)*512 + saK];
      }
      #pragma unroll
      for (int i=0;i<6;++i){
        const int s = tid + (i<<9);
        const int gg = s>>10, w1 = s&1023, row = w1>>3, kc = (w1&7)<<3;
        vb[i] = *(const uint4*)&Wd[(size_t)((gg<<9) + (bx<<7) + row)*512 + kc];
      }
    }
    for (int kt=0; kt<8; ++kt){
      __syncthreads();
      #pragma unroll
      for (int i=0;i<2;++i){
        const int row = saRow0 + (i<<6);
        *(uint4*)&lsA[row*72 + saK] = va[i];
      }
      #pragma unroll
      for (int i=0;i<6;++i){
        const int s = tid + (i<<9);
        const int gg = s>>10, w1 = s&1023, row = w1>>3, kc = (w1&7)<<3;
        *(uint4*)&lsB[((gg<<7)+row)*72 + kc] = vb[i];
      }
      __syncthreads();
      if (kt < 7){
        const int ko = (kt+1)<<6;
        #pragma unroll
        for (int i=0;i<2;++i){
          const int row = saRow0 + (i<<6);
          va[i] = *(const uint4*)&hin[(size_t)(bm+row)*512 + ko + saK];
        }
        #pragma unroll
        for (int i=0;i<6;++i){
          const int s = tid + (i<<9);
          const int gg = s>>10, w1 = s&1023, row = w1>>3, kc = (w1&7)<<3;
          vb[i] = *(const uint4*)&Wd[(size_t)((gg<<9) + (bx<<7) + row)*512 + ko + kc];
        }
      }
      #pragma unroll
      for (int ks=0;ks<2;++ks){
        short8 af[4];
        #pragma unroll
        for (int mi2=0;mi2<4;++mi2)
          af[mi2] = *(const short8*)&lsA[(wm + (mi2<<4) + l15)*72 + (ks<<5) + (l4<<3)];
        short8 bf[3][2];
        #pragma unroll
        for (int gg=0;gg<3;++gg)
          #pragma unroll
          for (int ni2=0;ni2<2;++ni2)
            bf[gg][ni2] = *(const short8*)&lsB[((gg<<7) + (wc<<5) + (ni2<<4) + l15)*72 + (ks<<5) + (l4<<3)];
        #pragma unroll
        for (int gg=0;gg<3;++gg)
          #pragma unroll
          for (int mi2=0;mi2<4;++mi2)
            #pragma unroll
            for (int ni2=0;ni2<2;++ni2)
              acc[gg][mi2][ni2] = __builtin_amdgcn_mfma_f32_16x16x32_bf16(af[mi2], bf[gg][ni2], acc[gg][mi2][ni2], 0,0,0);
      }
    }
    // epilogue: gates + logit partials
    const int bb = by>>1;
    const float* sp = sproj_t + (size_t)bb*TH_;
    const int jbase = (bx<<7) + (wc<<5);
    float spv[3][2], wcv[3][2], bhnv[2], dwv[2];
    #pragma unroll
    for (int ni2=0;ni2<2;++ni2){
      const int j = jbase + (ni2<<4) + l15;
      spv[0][ni2] = sp[j]; spv[1][ni2] = sp[512+j]; spv[2][ni2] = sp[1024+j];
      wcv[0][ni2] = wchk[j]; wcv[1][ni2] = wchk[512+j]; wcv[2][ni2] = wchk[1024+j];
      bhnv[ni2] = dbhh[1024+j];
      dwv[ni2] = decW[j];
    }
    const float* ckrow = checked + ((size_t)(bb*33 + tstep))*Y_;
    float lrow[4][4];
    #pragma unroll
    for (int mi2=0;mi2<4;++mi2)
      #pragma unroll
      for (int q=0;q<4;++q) lrow[mi2][q] = 0.f;
    #pragma unroll
    for (int mi2=0;mi2<4;++mi2){
      #pragma unroll
      for (int q=0;q<4;++q){
        const int row = bm + wm + (mi2<<4) + (l4<<2) + q;
        const float ck = ckrow[row & 255];
        #pragma unroll
        for (int ni2=0;ni2<2;++ni2){
          const int j = jbase + (ni2<<4) + l15;
          const float g0 = b2f(gib[(size_t)row*TH_ + j]);
          const float g1 = b2f(gib[(size_t)row*TH_ + 512 + j]);
          const float g2 = b2f(gib[(size_t)row*TH_ + 1024 + j]);
          const float hold = b2f(hin[(size_t)row*H_ + j]);
          const float r  = sigf(g0 + spv[0][ni2] + ck*wcv[0][ni2] + acc[0][mi2][ni2][q]);
          const float zg = sigf(g1 + spv[1][ni2] + ck*wcv[1][ni2] + acc[1][mi2][ni2][q]);
          const float n  = tanh_fast(g2 + spv[2][ni2] + ck*wcv[2][ni2] + r*(acc[2][mi2][ni2][q] + bhnv[ni2]));
          const float h2 = (1.f - zg)*n + zg*hold;
          hout[(size_t)row*H_ + j] = f2b(h2);
          lrow[mi2][q] += h2 * dwv[ni2];
        }
      }
    }
    #pragma unroll
    for (int mi2=0;mi2<4;++mi2)
      #pragma unroll
      for (int q=0;q<4;++q){
        float v = lrow[mi2][q];
        v += __shfl_xor(v,1); v += __shfl_xor(v,2); v += __shfl_xor(v,4); v += __shfl_xor(v,8);
        if (l15==0){
          const int row = bm + wm + (mi2<<4) + (l4<<2) + q;
          atomicAdd(&logitsW[row], v);
        }
      }
  } else {
    // ---------------- chk role (step tstep-1) ----------------
    if (tstep == 0) return;
    const int km1 = tstep - 1;
    const int cid = blockIdx.x - 256;     // 0..63
    const int bm = cid<<7;
    const int half = tid>>8;
    const int tidh = tid&255;
    const int w4 = tidh>>6, lane = tidh&63;
    const int wm = (w4>>1)<<6, wn = (w4&1)<<6;
    const int rs = tidh>>1;
    const int khh = (tidh&1)<<5;
    const int l15 = lane&15, l4 = lane>>4;
    ushort* lsA = smem + half*16384;
    ushort* lsB = lsA + 8192;
    float rsum[4][4];
    #pragma unroll
    for (int mi=0;mi<4;++mi)
      #pragma unroll
      for (int q=0;q<4;++q) rsum[mi][q] = 0.f;

    for (int p=0;p<2;++p){
      const int bn = ((p<<1) + half)<<7;
      f32x4 acc[4][4];
      #pragma unroll
      for (int i=0;i<4;++i)
        #pragma unroll
        for (int jj=0;jj<4;++jj) acc[i][jj] = 0.f;
      const ushort* pa = hin + (size_t)(bm+rs)*512 + khh;
      const ushort* pb = Wchk2b + (size_t)(bn+rs)*512 + khh;
      uint4 va[4], vb[4];
      #pragma unroll
      for (int i=0;i<4;++i){ va[i] = *(const uint4*)(pa + i*8); vb[i] = *(const uint4*)(pb + i*8); }
      for (int kt=0; kt<8; ++kt){
        __syncthreads();
        #pragma unroll
        for (int i=0;i<4;++i){
          const int c = ((tidh&1)<<2) + i;
          *(uint4*)&lsA[(size_t)((c<<7) + rs)<<3] = va[i];
          *(uint4*)&lsB[(size_t)((c<<7) + rs)<<3] = vb[i];
        }
        __syncthreads();
        if (kt < 7){
          const ushort* qa = pa + (size_t)(kt+1)*64;
          const ushort* qb = pb + (size_t)(kt+1)*64;
          #pragma unroll
          for (int i=0;i<4;++i){ va[i] = *(const uint4*)(qa + i*8); vb[i] = *(const uint4*)(qb + i*8); }
        }
        #pragma unroll
        for (int ks=0;ks<2;++ks){
          const int ch = (ks<<2) + l4;
          short8 af[4], bf[4];
          #pragma unroll
          for (int mi=0;mi<4;++mi) af[mi] = *(const short8*)&lsA[(size_t)((ch<<7) + wm + (mi<<4) + l15)<<3];
          #pragma unroll
          for (int ni=0;ni<4;++ni) bf[ni] = *(const short8*)&lsB[(size_t)((ch<<7) + wn + (ni<<4) + l15)<<3];
          #pragma unroll
          for (int mi=0;mi<4;++mi)
            #pragma unroll
            for (int ni=0;ni<4;++ni)
              acc[mi][ni] = __builtin_amdgcn_mfma_f32_16x16x32_bf16(af[mi], bf[ni], acc[mi][ni], 0,0,0);
        }
      }
      // fold tanh(u)*w2 into rsum
      #pragma unroll
      for (int mi=0;mi<4;++mi){
        #pragma unroll
        for (int ni=0;ni<4;++ni){
          const int col = bn + wn + (ni<<4) + l15;
          const float w2v = cw2[col];
          const int row0 = bm + wm + (mi<<4) + (l4<<2);
          #pragma unroll
          for (int q=0;q<4;++q){
            const float u = acc[mi][ni][q] + b2f(chkbase[(size_t)(row0+q)*H_ + col]);
            rsum[mi][q] += tanh_fast(u) * w2v;
          }
        }
      }
    }
    __syncthreads();   // staging LDS no longer needed; safe to overlay
    float* cred2 = (float*)smem;   // [4][128]
    #pragma unroll
    for (int mi=0;mi<4;++mi)
      #pragma unroll
      for (int q=0;q<4;++q){
        float v = rsum[mi][q];
        v += __shfl_xor(v,1); v += __shfl_xor(v,2); v += __shfl_xor(v,4); v += __shfl_xor(v,8);
        if (l15==0){
          const int widx = half*2 + (wn>>6);
          cred2[widx*128 + wm + (mi<<4) + (l4<<2) + q] = v;
        }
      }
    __syncthreads();
    if (tid < 128){
      const float tot = cred2[tid] + cred2[128+tid] + cred2[256+tid] + cred2[384+tid];
      stf_sc1(chkdot + bm + tid, tot);
    }
    __syncthreads();   // drain sc1 chkdot stores
    if (tid==0) slast = atomicAdd(counter, 1u);
    __syncthreads();
    if (slast != 63u) return;

    // ---------- loss (last chk block only) ----------
    float* sm = (float*)smem;
    // chk loss over all 8192 rows
    float wsum = 0.f;
    {
      const int r0 = tid*16;
      float cd[16];
      ld16_sc1(chkdot + r0, cd);
      const float b2v = cb2v[0];
      #pragma unroll
      for (int i=0;i<16;++i){
        const int row = r0 + i, bb = row>>8, yy = row&255;
        const float u = cd[i] + b2v;
        const float c = checked[((size_t)bb*33 + km1 + 1)*Y_ + yy];
        const float yt = yv[((size_t)bb*SOUT_ + km1)*Y_ + yy];
        wsum += yt * (c*splus(-u) + (1.f-c)*splus(u));
      }
    }
    sm[tid] = wsum; __syncthreads();
    for (int o=256;o;o>>=1){ if (tid<o) sm[tid] += sm[tid+o]; __syncthreads(); }
    if (tid==0) atomicAdd(accv+1, sm[0]);
    __syncthreads();
    // logit softmax loss (logitsR written by previous launch)
    {
      const int bb = tid>>4, part = tid&15;
      const float* lg = logitsR + bb*Y_ + part*16;
      float lv[16];
      float m = -1e30f;
      #pragma unroll
      for (int i=0;i<16;++i){ lv[i] = lg[i]; m = fmaxf(m, lv[i]); }
      m = fmaxf(m, __shfl_xor(m,1)); m = fmaxf(m, __shfl_xor(m,2));
      m = fmaxf(m, __shfl_xor(m,4)); m = fmaxf(m, __shfl_xor(m,8));
      float se = 0.f;
      #pragma unroll
      for (int i=0;i<16;++i) se += __expf(lv[i]-m);
      se += __shfl_xor(se,1); se += __shfl_xor(se,2); se += __shfl_xor(se,4); se += __shfl_xor(se,8);
      const float lse = m + logf(se);
      const float* yr = yv + ((size_t)bb*SOUT_ + km1)*Y_ + part*16;
      float pl = 0.f;
      #pragma unroll
      for (int i=0;i<16;++i) pl += yr[i]*(lv[i]-lse);
      pl += __shfl_xor(pl,1); pl += __shfl_xor(pl,2); pl += __shfl_xor(pl,4); pl += __shfl_xor(pl,8);
      sm[tid] = (part==0) ? pl : 0.f;
    }
    __syncthreads();
    for (int o=256;o;o>>=1){ if (tid<o) sm[tid] += sm[tid+o]; __syncthreads(); }
    if (tid==0) atomicAdd(accv+0, -sm[0]);
    // resets for buffer reuse (visible to later launches via kernel boundary)
    for (int i=tid; i<8192; i+=512) logitsR[i] = 0.f;
    if (tid==0) counter[0] = 0u;
  }
}

__global__ void k_final(const float* __restrict__ acc, float* __restrict__ out)
{
  if (threadIdx.x==0){
    const float ls = acc[0], cls = acc[1], ys = acc[2];
    out[0] = (ls+cls)/ys; out[1] = ls/ys; out[2] = cls/ys;
  }
}

// ---------------- host ----------------
extern "C" void kernel_launch(void* const* d_in, const int* in_sizes, int n_in,
                              void* d_out, int out_size, void* d_ws, size_t ws_size,
                              hipStream_t stream)
{
  (void)in_sizes; (void)n_in; (void)out_size;
  const int*   x      = (const int*)d_in[0];
  const int*   akey   = (const int*)d_in[1];
  const int*   atype  = (const int*)d_in[2];
  const int*   croom  = (const int*)d_in[3];
  const float* checked= (const float*)d_in[4];
  const float* yv     = (const float*)d_in[5];
  const float* emb    = (const float*)d_in[6];
  const float* attab  = (const float*)d_in[7];
  const float* eWihF  = (const float*)d_in[8];
  const float* eWhhF  = (const float*)d_in[9];
  const float* ebihF  = (const float*)d_in[10];
  const float* ebhhF  = (const float*)d_in[11];
  const float* eWihB  = (const float*)d_in[12];
  const float* eWhhB  = (const float*)d_in[13];
  const float* ebihB  = (const float*)d_in[14];
  const float* ebhhB  = (const float*)d_in[15];
  const float* transW = (const float*)d_in[16];
  const float* transb = (const float*)d_in[17];
  const float* mergeW = (const float*)d_in[18];
  const float* mergeb = (const float*)d_in[19];
  const float* dWih   = (const float*)d_in[20];
  const float* dWhh   = (const float*)d_in[21];
  const float* dbih   = (const float*)d_in[22];
  const float* dbhh   = (const float*)d_in[23];
  const float* dW     = (const float*)d_in[24];
  const float* cW1    = (const float*)d_in[26];
  const float* cb1    = (const float*)d_in[27];
  const float* cW2    = (const float*)d_in[28];
  const float* cb2    = (const float*)d_in[29];

  char* base = (char*)d_ws;
  size_t off = 0;
  auto alloc = [&](size_t bytes)->char*{ char* p = base + off; off += (bytes + 255) & ~(size_t)255; return p; };

  float*  accv   = (float*)alloc(256);
  ushort* embxs  = (ushort*)alloc((size_t)SIN_*B_*E_*2);
  ushort* aemb   = (ushort*)alloc((size_t)Y_*E_*2);
  ushort* aembT  = (ushort*)alloc((size_t)Y_*E_*2);
  float*  avec   = (float*)alloc((size_t)Y_*32*4);
  ushort* yprev  = (ushort*)alloc((size_t)SOUT_*B_*Y_*2);
  ushort* acat   = (ushort*)alloc((size_t)SOUT_*B_*512*2);
  ushort* gi_fb  = (ushort*)alloc((size_t)2*SIN_*B_*TH_*2);
  ushort* gi_f   = gi_fb;
  ushort* gi_b   = gi_fb + (size_t)SIN_*B_*TH_;
  ushort* gibase = gi_fb;
  ushort* encout = (ushort*)alloc((size_t)B_*SIN_*1024*2);
  ushort* encoutT= (ushort*)alloc((size_t)B_*1024*SIN_*2);
  float*  hTf    = (float*)alloc((size_t)B_*H_*4);
  float*  hTb    = (float*)alloc((size_t)B_*H_*4);
  float*  h0dec  = (float*)alloc((size_t)B_*H_*4);
  ushort* esum   = (ushort*)alloc((size_t)B_*SIN_*E_*2);
  float*  scores = (float*)alloc((size_t)B_*Y_*SIN_*4);
  ushort* alpha  = (ushort*)alloc((size_t)B_*Y_*SIN_*2);
  ushort* att    = (ushort*)alloc((size_t)8192*1024*2);
  ushort* chkbase= (ushort*)alloc((size_t)8192*H_*2);
  float*  addy   = (float*)alloc((size_t)Y_*TH_*4);
  float*  addcy  = (float*)alloc((size_t)Y_*H_*4);
  float*  sproj  = (float*)alloc((size_t)SOUT_*B_*TH_*4);
  float*  wchk   = (float*)alloc((size_t)TH_*4);
  float*  dbhhrz = (float*)alloc((size_t)TH_*4);
  ushort* WihFb  = (ushort*)alloc((size_t)TH_*E_*2);
  ushort* WihBb  = (ushort*)alloc((size_t)TH_*E_*2);
  ushort* Wtrb   = (ushort*)alloc((size_t)E_*1024*2);
  ushort* Wattb  = (ushort*)alloc((size_t)TH_*1024*2);
  ushort* Wcat2b = (ushort*)alloc((size_t)TH_*512*2);
  ushort* W1attb = (ushort*)alloc((size_t)H_*1024*2);
  ushort* Wdecb  = (ushort*)alloc((size_t)TH_*512*2);
  ushort* Wchk2b = (ushort*)alloc((size_t)512*512*2);
  ushort* h2bA   = (ushort*)alloc((size_t)8192*H_*2);
  ushort* h2bB   = (ushort*)alloc((size_t)8192*H_*2);
  float*  chkdot = (float*)alloc((size_t)8192*4);
  float*  L0     = (float*)alloc((size_t)8192*4);
  float*  L1     = (float*)alloc((size_t)8192*4);
  ushort* hG     = (ushort*)alloc((size_t)2*2*32*512*2);
  uint*   flags  = (uint*)alloc((size_t)256*4);
  uint*   counter= (uint*)alloc((size_t)256);

  if (off > ws_size){ k_wsfail<<<1,1,0,stream>>>((float*)d_out); return; }

  float* outp = (float*)d_out;

  k_init<<<dim3(1), dim3(64), 0, stream>>>(accv);
  k_init_enc<<<dim3(64), dim3(256), 0, stream>>>(flags, hG);
  k_ysum<<<dim3(256), dim3(256), 0, stream>>>(yv, accv);
  k_lookup<<<dim3(2048), dim3(256), 0, stream>>>(x, akey, atype, croom, yv, emb, attab,
                                                 embxs, aemb, aembT, avec, acat, yprev);
  k_convall<<<dim3(2048), dim3(256), 0, stream>>>(eWihF, eWihB, transW, dWih, cW1, dWhh,
                                                  WihFb, WihBb, Wtrb, Wattb, Wcat2b, W1attb, Wdecb, Wchk2b);
  k_prep2<<<dim3(1024), dim3(256), 0, stream>>>(avec, dWih, dbih, cW1, cb1, dbhh,
                                                addy, addcy, wchk, dbhhrz);

  // encoder input projections (bias folded in)
  gemm_nt<(GF_BIAS|GF_WBF16)><<<dim3(12,32,1), dim3(256), 0, stream>>>(
    embxs, WihFb, ebihF, nullptr, 0, nullptr, gi_f, TH_, E_, E_, E_, 0, 0L,0L,0L, nullptr);
  gemm_nt<(GF_BIAS|GF_WBF16)><<<dim3(12,32,1), dim3(256), 0, stream>>>(
    embxs, WihBb, ebihB, nullptr, 0, nullptr, gi_b, TH_, E_, E_, E_, 0, 0L,0L,0L, nullptr);

  enc_persist<<<dim3(64), dim3(256), 0, stream>>>(eWhhF, eWhhB, ebhhF, ebhhB, gi_f, gi_b,
                                                  hG, flags, encout, encoutT, hTf, hTb);

  // esum = bf16( tanh(enc_out @ trans_W^T + b) + emb )
  gemm_nt<(GF_BIAS|GF_TANH|GF_ESUM|GF_WBF16)><<<dim3(2,32,1), dim3(256), 0, stream>>>(
    encout, Wtrb, transb, nullptr, 0, nullptr, esum, E_, 1024, 1024, 1024, 0, 0L,0L,0L, embxs);

  // scores[b] = action_emb @ embsum_b^T
  gemm_nt<GF_WF32><<<dim3(1,2,32), dim3(256), 0, stream>>>(
    aemb, esum, nullptr, nullptr, 0, scores, nullptr, SIN_, E_, E_, E_, 0,
    0L, (long)SIN_*E_, (long)Y_*SIN_, nullptr);
  k_softmax<<<dim3(2048), dim3(256), 0, stream>>>(scores, alpha);

  // attention[b] = alpha_b @ enc_out_b
  gemm_nt<GF_WBF16><<<dim3(8,2,32), dim3(256), 0, stream>>>(
    alpha, encoutT, nullptr, nullptr, 0, nullptr, att, 1024, SIN_, SIN_, SIN_, 0,
    (long)Y_*SIN_, (long)1024*SIN_, (long)Y_*1024, nullptr);

  k_merge<<<dim3(32), dim3(512), 0, stream>>>(hTf, hTb, mergeW, mergeb, h0dec);

  // yemb -> acat[:,256:512]
  gemm_nt<GF_WBF16><<<dim3(2,8,1), dim3(256), 0, stream>>>(
    yprev, aembT, nullptr, nullptr, 0, nullptr, acat+256, 512, Y_, Y_, Y_, 0, 0L,0L,0L, nullptr);
  // sproj = acat @ Wcat2^T + dbhh_rz
  gemm_nt<(GF_BIAS|GF_WF32)><<<dim3(12,8,1), dim3(256), 0, stream>>>(
    acat, Wcat2b, dbhhrz, nullptr, 0, sproj, nullptr, TH_, 512, 512, 512, 0, 0L,0L,0L, nullptr);

  // gi_base = att @ W_att^T + add_y[y]   ;  chk_base = att @ W1_att^T + addc_y[y]
  gemm_nt<(GF_WBF16|GF_ADDY)><<<dim3(12,64,1), dim3(256), 0, stream>>>(
    att, Wattb, nullptr, addy, TH_, nullptr, gibase, TH_, 1024, 1024, 1024, 0, 0L,0L,0L, nullptr);
  gemm_nt<(GF_WBF16|GF_ADDY)><<<dim3(4,64,1), dim3(256), 0, stream>>>(
    att, W1attb, nullptr, addcy, H_, nullptr, chkbase, H_, 1024, 1024, 1024, 0, 0L,0L,0L, nullptr);

  k_bcast<<<dim3(4096), dim3(256), 0, stream>>>(h0dec, h2bA, L0, L1, counter);

  for (int k=0; k<=SOUT_; ++k){
    const ushort* hin = (k&1) ? h2bB : h2bA;     // H(k)
    ushort* hout      = (k&1) ? h2bA : h2bB;     // H(k+1)
    float* LW = (k&1) ? L1 : L0;                 // logits of step k
    float* LR = (k&1) ? L0 : L1;                 // logits of step k-1
    const int ks = (k < SOUT_) ? k : (SOUT_-1);
    dec_step<<<dim3(320), dim3(512), 0, stream>>>(
      hin, hout, Wdecb, gibase, sproj + (size_t)ks*B_*TH_, wchk, dbhh, checked,
      dW, Wchk2b, chkbase, cW2, cb2, yv, LW, LR, chkdot, counter, accv, k);
  }
  k_final<<<dim3(1), dim3(1), 0, stream>>>(accv, outp);
}

// Round 6
// 4945.002 us; speedup vs baseline: 1.3466x; 1.3466x over previous
//
#include <hip/hip_runtime.h>

typedef unsigned short ushort;
typedef unsigned int uint;
typedef __attribute__((ext_vector_type(8))) short short8;
typedef __attribute__((ext_vector_type(4))) float f32x4;
typedef __attribute__((ext_vector_type(4))) uint u32x4;

#define DEVI __device__ __forceinline__

#define B_ 32
#define SIN_ 128
#define SOUT_ 32
#define Y_ 256
#define H_ 512
#define E_ 256
#define TH_ 1536

DEVI float b2f(ushort u){ return __uint_as_float(((uint)u)<<16); }
DEVI ushort f2b(float f){ uint x = __float_as_uint(f); return (ushort)((x + 0x7FFFu + ((x>>16)&1u)) >> 16); }
DEVI float sigf(float x){ return 1.f/(1.f+__expf(-x)); }
DEVI float tanh_fast(float x){ return 2.f/(1.f+__expf(-2.f*x)) - 1.f; }
DEVI float splus(float x){ return fmaxf(x,0.f) + log1pf(__expf(-fabsf(x))); }
DEVI short8 cvt8(u32x4 v){ return __builtin_bit_cast(short8, v); }

// sc0 sc1 = coherent through Infinity Cache (cross-XCD visible without fences)
DEVI uint ld_flag(const uint* p){
  uint r;
  asm volatile("global_load_dword %0, %1, off sc0 sc1\n\ts_waitcnt vmcnt(0)"
               : "=v"(r) : "v"(p) : "memory");
  return r;
}
DEVI void st_flag(uint* p, uint v){
  asm volatile("global_store_dword %0, %1, off sc0 sc1" :: "v"(p), "v"(v) : "memory");
}
DEVI void st_h16(ushort* p, uint v){
  asm volatile("global_store_short %0, %1, off sc0 sc1" :: "v"(p), "v"(v) : "memory");
}
DEVI void stf_sc1(float* p, float v){
  asm volatile("global_store_dword %0, %1, off sc0 sc1" :: "v"(p), "v"(__float_as_uint(v)) : "memory");
}
// 16 contiguous floats, coherent
DEVI void ld16_sc1(const float* p, float* o){
  u32x4 r0,r1,r2,r3;
  asm volatile("global_load_dwordx4 %0, %4, off sc0 sc1\n\t"
               "global_load_dwordx4 %1, %4, off offset:16 sc0 sc1\n\t"
               "global_load_dwordx4 %2, %4, off offset:32 sc0 sc1\n\t"
               "global_load_dwordx4 %3, %4, off offset:48 sc0 sc1\n\t"
               "s_waitcnt vmcnt(0)"
               : "=&v"(r0),"=&v"(r1),"=&v"(r2),"=&v"(r3) : "v"(p) : "memory");
  *(u32x4*)(o) = r0; *(u32x4*)(o+4) = r1; *(u32x4*)(o+8) = r2; *(u32x4*)(o+12) = r3;
}

// ---------------- init / reductions ----------------
__global__ void k_init(float* acc){ if (threadIdx.x < 4) acc[threadIdx.x] = 0.f; }

__global__ void k_wsfail(float* out){ out[0]=1.2345e8f; out[1]=2.3456e8f; out[2]=3.4567e8f; }

__global__ void k_init_enc(uint* __restrict__ flags, ushort* __restrict__ hG)
{
  const int id = blockIdx.x*256 + threadIdx.x;
  if (id < 256) flags[id] = 0u;
  if (id < 8192) ((uint4*)hG)[id] = make_uint4(0,0,0,0);
}

__global__ __launch_bounds__(256) void k_ysum(const float* __restrict__ yv, float* __restrict__ acc)
{
  __shared__ float red[256];
  float s = 0.f;
  for (long i = (long)blockIdx.x*256 + threadIdx.x; i < (long)B_*SOUT_*Y_; i += (long)gridDim.x*256) s += yv[i];
  red[threadIdx.x] = s; __syncthreads();
  for (int o=128;o;o>>=1){ if ((int)threadIdx.x<o) red[threadIdx.x] += red[threadIdx.x+o]; __syncthreads(); }
  if (threadIdx.x==0) atomicAdd(acc+2, red[0]);
}

// ---------------- embedding / lookup ----------------
__global__ void k_lookup(const int* __restrict__ x, const int* __restrict__ akey,
                         const int* __restrict__ atype, const int* __restrict__ croom,
                         const float* __restrict__ yv,
                         const float* __restrict__ emb, const float* __restrict__ attab,
                         ushort* __restrict__ embxs, ushort* __restrict__ aemb,
                         ushort* __restrict__ aembT, float* __restrict__ avec,
                         ushort* __restrict__ acat, ushort* __restrict__ yprev)
{
  const long N1 = (long)SIN_*B_*E_;
  const long N2 = (long)Y_*E_;
  const long N3 = (long)Y_*32;
  const long N4 = (long)SOUT_*B_*E_;
  const long N5 = (long)SOUT_*B_*Y_;
  for (long i = (long)blockIdx.x*blockDim.x + threadIdx.x; i < N1+N2+N3+N4+N5; i += (long)gridDim.x*blockDim.x){
    long id = i;
    if (id < N1){
      int e = id & 255; long sb = id >> 8; int bb = (int)(sb & 31); int s = (int)(sb >> 5);
      embxs[id] = f2b(emb[(size_t)x[bb*SIN_ + s]*E_ + e]);
    } else if ((id -= N1) < N2){
      int e = (int)(id & 255), yy = (int)(id >> 8);
      ushort v = f2b(emb[(size_t)akey[yy]*E_ + e]);
      aemb[yy*E_ + e] = v;
      aembT[e*Y_ + yy] = v;
    } else if ((id -= N2) < N3){
      int a = (int)(id & 31), yy = (int)(id >> 5);
      avec[yy*32 + a] = attab[atype[yy]*32 + a];
    } else if ((id -= N3) < N4){
      int e = (int)(id & 255); long tb = id >> 8; int bb = (int)(tb & 31); int t = (int)(tb >> 5);
      acat[(size_t)tb*512 + e] = f2b(emb[(size_t)croom[bb*SOUT_ + t]*E_ + e]);
    } else { id -= N4;
      int yy = (int)(id & 255); long tb = id >> 8; int bb = (int)(tb & 31); int t = (int)(tb >> 5);
      yprev[id] = (t == 0) ? (ushort)0 : f2b(yv[((size_t)bb*SOUT_ + (t-1))*Y_ + yy]);
    }
  }
}

// all f32->bf16 weight conversions in one kernel
__global__ __launch_bounds__(256)
void k_convall(const float* __restrict__ eWihF, const float* __restrict__ eWihB,
               const float* __restrict__ transW, const float* __restrict__ dWih,
               const float* __restrict__ cW1, const float* __restrict__ dWhh,
               ushort* __restrict__ WihFb, ushort* __restrict__ WihBb,
               ushort* __restrict__ Wtrb, ushort* __restrict__ Wattb,
               ushort* __restrict__ Wcat2b, ushort* __restrict__ W1attb,
               ushort* __restrict__ Wdecb, ushort* __restrict__ Wchk2b)
{
  const long N1 = 393216;
  const long N2 = 393216;
  const long N3 = 262144;
  const long N4 = 1572864;
  const long N5 = 393216;
  const long N6 = 393216;
  const long N7 = 524288;
  const long N8 = 786432;
  const long N9 = 262144;
  const long NT = N1+N2+N3+N4+N5+N6+N7+N8+N9;
  for (long i = (long)blockIdx.x*256 + threadIdx.x; i < NT; i += (long)gridDim.x*256){
    long id = i;
    if (id < N1){ WihFb[id] = f2b(eWihF[id]); }
    else if ((id -= N1) < N2){ WihBb[id] = f2b(eWihB[id]); }
    else if ((id -= N2) < N3){ Wtrb[id] = f2b(transW[id]); }
    else if ((id -= N3) < N4){
      const long r = id>>10, c = id&1023;
      Wattb[id] = f2b(dWih[r*1569 + c]);
    }
    else if ((id -= N4) < N5){
      const long r = id>>8, c = id&255;
      Wcat2b[r*512 + c] = f2b(dWih[r*1569 + 1025 + c]);
    }
    else if ((id -= N5) < N6){
      const long r = id>>8, c = id&255;
      Wcat2b[r*512 + 256 + c] = f2b(dWih[r*1569 + 1313 + c]);
    }
    else if ((id -= N6) < N7){
      const long r = id>>10, c = id&1023;
      W1attb[id] = f2b(cW1[r*1568 + c]);
    }
    else if ((id -= N7) < N8){ Wdecb[id] = f2b(dWhh[id]); }
    else { id -= N8;
      const long r = id>>9, c = id&511;
      Wchk2b[id] = f2b(cW1[r*1568 + 1056 + c]);
    }
  }
}

// add_y, addc_y, wchk, dbhh_rz
__global__ void k_prep2(const float* __restrict__ avec, const float* __restrict__ decWih,
                        const float* __restrict__ dbih, const float* __restrict__ cW1,
                        const float* __restrict__ cb1, const float* __restrict__ dbhh,
                        float* __restrict__ addy, float* __restrict__ addcy,
                        float* __restrict__ wchk, float* __restrict__ dbhhrz)
{
  const long NA = (long)Y_*TH_;
  const long NB = (long)Y_*H_;
  for (long i = (long)blockIdx.x*blockDim.x + threadIdx.x; i < NA+NB+TH_+TH_; i += (long)gridDim.x*blockDim.x){
    long id = i;
    if (id < NA){
      int n = (int)(id % TH_), yy = (int)(id / TH_);
      float s = dbih[n];
      const float* wr = decWih + (size_t)n*1569 + 1281;
      const float* av = avec + yy*32;
      #pragma unroll
      for (int a=0;a<32;++a) s += av[a]*wr[a];
      addy[id] = s;
    } else if ((id -= NA) < NB){
      int n = (int)(id & 511), yy = (int)(id >> 9);
      float s = cb1[n];
      const float* wr = cW1 + (size_t)n*1568 + 1024;
      const float* av = avec + yy*32;
      #pragma unroll
      for (int a=0;a<32;++a) s += av[a]*wr[a];
      addcy[id] = s;
    } else if ((id -= NB) < TH_){
      wchk[id] = decWih[(size_t)id*1569 + 1024];
    } else { id -= TH_;
      dbhhrz[id] = (id < 1024) ? dbhh[id] : 0.f;
    }
  }
}

// ---------------- bf16 NT GEMM: C[M,N] = A[M,K] @ W[N,K]^T  (MFMA 16x16x32) ----------------
#define GF_BIAS 1
#define GF_TANH 2
#define GF_WF32 4
#define GF_WBF16 8
#define GF_ADDY 32
#define GF_ESUM 128

template<int FLAGS>
__global__ __launch_bounds__(256)
void gemm_nt(const ushort* __restrict__ A, const ushort* __restrict__ W,
             const float* __restrict__ bias,
             const float* __restrict__ addy, int lday,
             float* __restrict__ Cf, ushort* __restrict__ Cb, int ldC,
             int K, int ldA, int ldW, int n0,
             long zA, long zW, long zC,
             const ushort* __restrict__ chkbase)
{
  const int z = blockIdx.z;
  A += (long)z*zA; W += (long)z*zW;
  const int bn = n0 + (blockIdx.x<<7);
  const int bm = (blockIdx.y<<7);
  const int tid = threadIdx.x;
  const int w = tid>>6, lane = tid&63;
  const int wm = (w>>1)<<6, wn = (w&1)<<6;
  const int rs = tid>>1;
  const int kh = (tid&1)<<5;
  __shared__ ushort lsA[8192];
  __shared__ ushort lsB[8192];
  f32x4 acc[4][4];
  #pragma unroll
  for (int i=0;i<4;++i)
    #pragma unroll
    for (int jj=0;jj<4;++jj) acc[i][jj] = 0.f;

  const ushort* pa = A + (size_t)(bm+rs)*ldA + kh;
  const ushort* pb = W + (size_t)(bn+rs)*ldW + kh;
  uint4 va[4], vb[4];
  #pragma unroll
  for (int i=0;i<4;++i){ va[i] = *(const uint4*)(pa + i*8); vb[i] = *(const uint4*)(pb + i*8); }
  const int nkt = K>>6;
  for (int kt=0; kt<nkt; ++kt){
    __syncthreads();
    #pragma unroll
    for (int i=0;i<4;++i){
      const int c = ((tid&1)<<2) + i;
      *(uint4*)&lsA[(size_t)((c<<7) + rs)<<3] = va[i];
      *(uint4*)&lsB[(size_t)((c<<7) + rs)<<3] = vb[i];
    }
    __syncthreads();
    if (kt+1 < nkt){
      const ushort* qa = pa + (size_t)(kt+1)*64;
      const ushort* qb = pb + (size_t)(kt+1)*64;
      #pragma unroll
      for (int i=0;i<4;++i){ va[i] = *(const uint4*)(qa + i*8); vb[i] = *(const uint4*)(qb + i*8); }
    }
    #pragma unroll
    for (int ks=0;ks<2;++ks){
      const int ch = (ks<<2) + (lane>>4);
      short8 af[4], bf[4];
      #pragma unroll
      for (int mi=0;mi<4;++mi) af[mi] = *(const short8*)&lsA[(size_t)((ch<<7) + wm + (mi<<4) + (lane&15))<<3];
      #pragma unroll
      for (int ni=0;ni<4;++ni) bf[ni] = *(const short8*)&lsB[(size_t)((ch<<7) + wn + (ni<<4) + (lane&15))<<3];
      #pragma unroll
      for (int mi=0;mi<4;++mi)
        #pragma unroll
        for (int ni=0;ni<4;++ni)
          acc[mi][ni] = __builtin_amdgcn_mfma_f32_16x16x32_bf16(af[mi], bf[ni], acc[mi][ni], 0,0,0);
    }
  }
  const long zc = (long)z*zC;
  #pragma unroll
  for (int mi=0;mi<4;++mi){
    #pragma unroll
    for (int ni=0;ni<4;++ni){
      const int col = bn + wn + (ni<<4) + (lane&15);
      const int row0 = bm + wm + (mi<<4) + ((lane>>4)<<2);
      float bv = 0.f;
      if (FLAGS & GF_BIAS) bv = bias[col];
      #pragma unroll
      for (int q=0;q<4;++q){
        const int row = row0 + q;
        float xv = acc[mi][ni][q] + bv;
        if (FLAGS & GF_ADDY) xv += addy[(size_t)(row&255)*lday + col];
        if (FLAGS & GF_TANH) xv = tanh_fast(xv);
        if (FLAGS & GF_ESUM) xv += b2f(chkbase[((size_t)(row&127)*32 + (row>>7))*256 + col]);
        if (FLAGS & GF_WF32)  Cf[zc + (size_t)row*ldC + col] = xv;
        if (FLAGS & GF_WBF16) Cb[zc + (size_t)row*ldC + col] = f2b(xv);
      }
    }
  }
}

// ---------------- persistent bi-GRU encoder (fence-free sc1 exchange, hi-only bf16 h) ----------------
__global__ __launch_bounds__(256,1)
void enc_persist(const float* __restrict__ Wf, const float* __restrict__ Wb,
                 const float* __restrict__ bhf, const float* __restrict__ bhb,
                 const ushort* __restrict__ gif, const ushort* __restrict__ gib,
                 ushort* __restrict__ hG, uint* __restrict__ flags,
                 ushort* __restrict__ encout, ushort* __restrict__ encoutT,
                 float* __restrict__ hTf, float* __restrict__ hTb)
{
  const int g = blockIdx.x;
  const int dir = g >> 5;
  const int j0 = (g & 31) << 4;
  const int tid = threadIdx.x;
  const int w = tid >> 6, lane = tid & 63;
  const int mi = w & 1, kh = w >> 1;
  const int l15 = lane & 15, l4 = lane >> 4;
  const int brow0 = mi*16 + l4*4;

  const float* W = dir ? Wb : Wf;
  const float* bh = dir ? bhb : bhf;
  const ushort* gi = dir ? gib : gif;

  __shared__ __align__(16) float cred[2][3][256];
  __shared__ float bhl[48];

  short8 bw[3][8];
  {
    const int kbase = kh*256 + l4*8;
    #pragma unroll
    for (int ni=0; ni<3; ++ni){
      const float* wr = W + (size_t)(ni*512 + j0 + l15)*512 + kbase;
      #pragma unroll
      for (int ks=0; ks<8; ++ks){
        const float4 f0 = *(const float4*)(wr + ks*32);
        const float4 f1 = *(const float4*)(wr + ks*32 + 4);
        short8 v;
        v[0]=(short)f2b(f0.x); v[1]=(short)f2b(f0.y); v[2]=(short)f2b(f0.z); v[3]=(short)f2b(f0.w);
        v[4]=(short)f2b(f1.x); v[5]=(short)f2b(f1.y); v[6]=(short)f2b(f1.z); v[7]=(short)f2b(f1.w);
        bw[ni][ks] = v;
      }
    }
  }
  if (tid < 48) bhl[tid] = bh[(tid>>4)*512 + j0 + (tid&15)];
  __syncthreads();

  float bh0r=0.f, bh1r=0.f, bh2r=0.f;
  if (kh==0){ bh0r = bhl[l15]; bh1r = bhl[16+l15]; bh2r = bhl[32+l15]; }
  float holdr[4] = {0.f,0.f,0.f,0.f};
  uint* myflag = flags + dir*32 + (g&31);

  for (int t=0; t<128; ++t){
    const int tt = dir ? (127 - t) : t;
    float giv0[4], giv1[4], giv2[4];
    if (kh==0){
      const ushort* girow = gi + ((size_t)tt*32 + brow0)*1536 + j0 + l15;
      #pragma unroll
      for (int q=0; q<4; ++q){
        giv0[q] = b2f(girow[q*1536]);
        giv1[q] = b2f(girow[q*1536 + 512]);
        giv2[q] = b2f(girow[q*1536 + 1024]);
      }
    }
    if (t){
      if ((tid>>6)==2 && (tid&63)<32){
        const uint* fp = flags + dir*32 + (tid&31);
        while (ld_flag(fp) < (uint)t) __builtin_amdgcn_s_sleep(2);
      }
      __syncthreads();
    }
    const ushort* hsrc = hG + ((size_t)((t&1)*2 + dir))*16384 + (size_t)(mi*16+l15)*512 + kh*256 + l4*8;
    u32x4 a0,a1,a2,a3,a4,a5,a6,a7;
    asm volatile(
      "global_load_dwordx4 %0, %8, off sc0 sc1\n\t"
      "global_load_dwordx4 %1, %8, off offset:64 sc0 sc1\n\t"
      "global_load_dwordx4 %2, %8, off offset:128 sc0 sc1\n\t"
      "global_load_dwordx4 %3, %8, off offset:192 sc0 sc1\n\t"
      "global_load_dwordx4 %4, %8, off offset:256 sc0 sc1\n\t"
      "global_load_dwordx4 %5, %8, off offset:320 sc0 sc1\n\t"
      "global_load_dwordx4 %6, %8, off offset:384 sc0 sc1\n\t"
      "global_load_dwordx4 %7, %8, off offset:448 sc0 sc1\n\t"
      "s_waitcnt vmcnt(0)"
      : "=&v"(a0),"=&v"(a1),"=&v"(a2),"=&v"(a3),"=&v"(a4),"=&v"(a5),"=&v"(a6),"=&v"(a7)
      : "v"(hsrc)
      : "memory");
    const short8 ah[8] = {cvt8(a0),cvt8(a1),cvt8(a2),cvt8(a3),cvt8(a4),cvt8(a5),cvt8(a6),cvt8(a7)};
    f32x4 acc[3]; acc[0]=0.f; acc[1]=0.f; acc[2]=0.f;
    #pragma unroll
    for (int ks=0; ks<8; ++ks){
      acc[0] = __builtin_amdgcn_mfma_f32_16x16x32_bf16(ah[ks], bw[0][ks], acc[0],0,0,0);
      acc[1] = __builtin_amdgcn_mfma_f32_16x16x32_bf16(ah[ks], bw[1][ks], acc[1],0,0,0);
      acc[2] = __builtin_amdgcn_mfma_f32_16x16x32_bf16(ah[ks], bw[2][ks], acc[2],0,0,0);
    }
    if (kh==1){
      #pragma unroll
      for (int ni=0; ni<3; ++ni) *(f32x4*)&cred[mi][ni][lane*4] = acc[ni];
    }
    __syncthreads();
    ushort hbs[4];
    if (kh==0){
      #pragma unroll
      for (int ni=0; ni<3; ++ni){
        const f32x4 o = *(const f32x4*)&cred[mi][ni][lane*4];
        acc[ni][0]+=o[0]; acc[ni][1]+=o[1]; acc[ni][2]+=o[2]; acc[ni][3]+=o[3];
      }
      ushort* dst = hG + ((size_t)(((t+1)&1)*2 + dir))*16384;
      #pragma unroll
      for (int q=0; q<4; ++q){
        const int b = brow0 + q;
        const float r  = sigf(giv0[q] + acc[0][q] + bh0r);
        const float zg = sigf(giv1[q] + acc[1][q] + bh1r);
        const float n  = tanh_fast(giv2[q] + r*(acc[2][q] + bh2r));
        const float h2 = (1.f - zg)*n + zg*holdr[q];
        holdr[q] = h2;
        const ushort hb = f2b(h2);
        hbs[q] = hb;
        if (t < 127) st_h16(dst + (size_t)b*512 + j0 + l15, (uint)hb);
      }
    }
    __syncthreads();   // drains kh==0 waves' sc1 h-stores before flag
    if (t < 127 && tid == 0) st_flag(myflag, (uint)(t+1));
    if (kh==0){
      #pragma unroll
      for (int q=0; q<4; ++q){
        const int b = brow0 + q;
        encout[((size_t)b*SIN_ + tt)*1024 + dir*H_ + j0 + l15] = hbs[q];
        encoutT[((size_t)b*1024 + dir*H_ + j0 + l15)*SIN_ + tt] = hbs[q];
      }
    }
  }
  if (kh==0){
    float* hT = dir ? hTb : hTf;
    #pragma unroll
    for (int q=0; q<4; ++q) hT[(size_t)(brow0+q)*H_ + j0 + l15] = holdr[q];
  }
}

// row softmax over SIN=128, one wave per row
__global__ __launch_bounds__(256) void k_softmax(const float* __restrict__ sc, ushort* __restrict__ al)
{
  const int row = blockIdx.x*4 + (threadIdx.x>>6);
  const int lane = threadIdx.x&63;
  const float* s = sc + (size_t)row*SIN_;
  const float2 v = *(const float2*)&s[lane*2];
  float m = fmaxf(v.x, v.y);
  #pragma unroll
  for (int o=1;o<64;o<<=1) m = fmaxf(m, __shfl_xor(m, o));
  const float e0 = __expf(v.x - m), e1 = __expf(v.y - m);
  float sum = e0 + e1;
  #pragma unroll
  for (int o=1;o<64;o<<=1) sum += __shfl_xor(sum, o);
  const float inv = 1.f/sum;
  ushort* a = al + (size_t)row*SIN_;
  const uint pkv = (uint)f2b(e0*inv) | ((uint)f2b(e1*inv)<<16);
  *(uint*)&a[lane*2] = pkv;
}

// h0_dec = tanh(hidden_cat @ merge_W^T + merge_b)
__global__ __launch_bounds__(512)
void k_merge(const float* __restrict__ hTf, const float* __restrict__ hTb,
             const float* __restrict__ mW, const float* __restrict__ mb,
             float* __restrict__ h0)
{
  const int b = blockIdx.x, j = threadIdx.x;
  __shared__ float hc[1024];
  for (int i=j; i<1024; i+=512){
    const int half = i >> 9, jj = i & 511;
    hc[i] = (b < 16) ? hTf[(size_t)(2*b + half)*H_ + jj] : hTb[(size_t)(2*(b-16) + half)*H_ + jj];
  }
  __syncthreads();
  float d = mb[j];
  const float* wr = mW + (size_t)j*1024;
  #pragma unroll 8
  for (int k=0;k<1024;k+=4){
    const float4 a = *(const float4*)&wr[k];
    const float4 hh = *(const float4*)&hc[k];
    d += a.x*hh.x + a.y*hh.y + a.z*hh.z + a.w*hh.w;
  }
  h0[(size_t)b*H_ + j] = tanh_fast(d);
}

__global__ void k_bcast(const float* __restrict__ h0, ushort* __restrict__ hb,
                        float* __restrict__ logits, uint* __restrict__ counter)
{
  for (long i = (long)blockIdx.x*blockDim.x + threadIdx.x; i < (long)8192*H_; i += (long)gridDim.x*blockDim.x){
    const int jj = (int)(i & 511); const long row = i >> 9; const int bb = (int)(row >> 8);
    hb[i] = f2b(h0[(size_t)bb*H_ + jj]);
    if (i < 8192) logits[i] = 0.f;
    if (i == 0) counter[0] = 0u;
  }
}

// ---------------- fused decoder recurrent GEMM + gates + logit partials ----------------
// grid (4, 64): bx = 128-j block, by = 128-row block. 512 threads = 8 waves (2 row x 4 col).
__global__ __launch_bounds__(512,1)
void gemm_dec(const ushort* __restrict__ A, const ushort* __restrict__ Wd,
              const ushort* __restrict__ gib, const float* __restrict__ sproj_t,
              const float* __restrict__ wchk, const float* __restrict__ dbhh,
              const float* __restrict__ checked, int t,
              const float* __restrict__ decW,
              ushort* __restrict__ h2bo, float* __restrict__ logits)
{
  const int bx = blockIdx.x;
  const int by = blockIdx.y;
  const int bm = by<<7;
  const int tid = threadIdx.x;
  const int w = tid>>6, lane = tid&63;
  const int wrh = w>>2, wc = w&3;
  const int wm = wrh<<6;
  const int l15 = lane&15, l4 = lane>>4;
  __shared__ ushort lsA[128*72];
  __shared__ ushort lsB[384*72];
  f32x4 acc[3][4][2];
  #pragma unroll
  for (int gg=0;gg<3;++gg)
    #pragma unroll
    for (int mi2=0;mi2<4;++mi2)
      #pragma unroll
      for (int ni2=0;ni2<2;++ni2) acc[gg][mi2][ni2] = 0.f;

  const int saRow0 = tid>>3, saK = (tid&7)<<3;
  uint4 va[2], vb[6];
  {
    #pragma unroll
    for (int i=0;i<2;++i){
      const int row = saRow0 + (i<<6);
      va[i] = *(const uint4*)&A[(size_t)(bm+row)*512 + saK];
    }
    #pragma unroll
    for (int i=0;i<6;++i){
      const int s = tid + (i<<9);
      const int gg = s>>10, w1 = s&1023, row = w1>>3, kc = (w1&7)<<3;
      vb[i] = *(const uint4*)&Wd[(size_t)((gg<<9) + (bx<<7) + row)*512 + kc];
    }
  }
  for (int kt=0; kt<8; ++kt){
    __syncthreads();
    #pragma unroll
    for (int i=0;i<2;++i){
      const int row = saRow0 + (i<<6);
      *(uint4*)&lsA[row*72 + saK] = va[i];
    }
    #pragma unroll
    for (int i=0;i<6;++i){
      const int s = tid + (i<<9);
      const int gg = s>>10, w1 = s&1023, row = w1>>3, kc = (w1&7)<<3;
      *(uint4*)&lsB[((gg<<7)+row)*72 + kc] = vb[i];
    }
    __syncthreads();
    if (kt < 7){
      const int ko = (kt+1)<<6;
      #pragma unroll
      for (int i=0;i<2;++i){
        const int row = saRow0 + (i<<6);
        va[i] = *(const uint4*)&A[(size_t)(bm+row)*512 + ko + saK];
      }
      #pragma unroll
      for (int i=0;i<6;++i){
        const int s = tid + (i<<9);
        const int gg = s>>10, w1 = s&1023, row = w1>>3, kc = (w1&7)<<3;
        vb[i] = *(const uint4*)&Wd[(size_t)((gg<<9) + (bx<<7) + row)*512 + ko + kc];
      }
    }
    #pragma unroll
    for (int ks=0;ks<2;++ks){
      short8 af[4];
      #pragma unroll
      for (int mi2=0;mi2<4;++mi2)
        af[mi2] = *(const short8*)&lsA[(wm + (mi2<<4) + l15)*72 + (ks<<5) + (l4<<3)];
      short8 bf[3][2];
      #pragma unroll
      for (int gg=0;gg<3;++gg)
        #pragma unroll
        for (int ni2=0;ni2<2;++ni2)
          bf[gg][ni2] = *(const short8*)&lsB[((gg<<7) + (wc<<5) + (ni2<<4) + l15)*72 + (ks<<5) + (l4<<3)];
      #pragma unroll
      for (int gg=0;gg<3;++gg)
        #pragma unroll
        for (int mi2=0;mi2<4;++mi2)
          #pragma unroll
          for (int ni2=0;ni2<2;++ni2)
            acc[gg][mi2][ni2] = __builtin_amdgcn_mfma_f32_16x16x32_bf16(af[mi2], bf[gg][ni2], acc[gg][mi2][ni2], 0,0,0);
    }
  }
  // epilogue: gates + logit partials
  const int bb = by>>1;
  const float* sp = sproj_t + (size_t)bb*TH_;
  const int jbase = (bx<<7) + (wc<<5);
  float spv[3][2], wcv[3][2], bhnv[2], dwv[2];
  #pragma unroll
  for (int ni2=0;ni2<2;++ni2){
    const int j = jbase + (ni2<<4) + l15;
    spv[0][ni2] = sp[j]; spv[1][ni2] = sp[512+j]; spv[2][ni2] = sp[1024+j];
    wcv[0][ni2] = wchk[j]; wcv[1][ni2] = wchk[512+j]; wcv[2][ni2] = wchk[1024+j];
    bhnv[ni2] = dbhh[1024+j];
    dwv[ni2] = decW[j];
  }
  const float* ckrow = checked + ((size_t)(bb*33 + t))*Y_;
  float lrow[4][4];
  #pragma unroll
  for (int mi2=0;mi2<4;++mi2)
    #pragma unroll
    for (int q=0;q<4;++q) lrow[mi2][q] = 0.f;
  #pragma unroll
  for (int mi2=0;mi2<4;++mi2){
    #pragma unroll
    for (int q=0;q<4;++q){
      const int row = bm + wm + (mi2<<4) + (l4<<2) + q;
      const float ck = ckrow[row & 255];
      #pragma unroll
      for (int ni2=0;ni2<2;++ni2){
        const int j = jbase + (ni2<<4) + l15;
        const float g0 = b2f(gib[(size_t)row*TH_ + j]);
        const float g1 = b2f(gib[(size_t)row*TH_ + 512 + j]);
        const float g2 = b2f(gib[(size_t)row*TH_ + 1024 + j]);
        const float hold = b2f(A[(size_t)row*H_ + j]);
        const float r  = sigf(g0 + spv[0][ni2] + ck*wcv[0][ni2] + acc[0][mi2][ni2][q]);
        const float zg = sigf(g1 + spv[1][ni2] + ck*wcv[1][ni2] + acc[1][mi2][ni2][q]);
        const float n  = tanh_fast(g2 + spv[2][ni2] + ck*wcv[2][ni2] + r*(acc[2][mi2][ni2][q] + bhnv[ni2]));
        const float h2 = (1.f - zg)*n + zg*hold;
        h2bo[(size_t)row*H_ + j] = f2b(h2);
        lrow[mi2][q] += h2 * dwv[ni2];
      }
    }
  }
  #pragma unroll
  for (int mi2=0;mi2<4;++mi2)
    #pragma unroll
    for (int q=0;q<4;++q){
      float v = lrow[mi2][q];
      v += __shfl_xor(v,1); v += __shfl_xor(v,2); v += __shfl_xor(v,4); v += __shfl_xor(v,8);
      if (l15==0){
        const int row = bm + wm + (mi2<<4) + (l4<<2) + q;
        atomicAdd(&logits[row], v);
      }
    }
}

// ---------------- chk-MLP GEMM + fused losses (last block elected) ----------------
// grid 256: bx = blockIdx&3 (128-col block of Wchk2), by = blockIdx>>2 (128-row block)
__global__ __launch_bounds__(256)
void chk_fused(const ushort* __restrict__ h2, const ushort* __restrict__ Wc,
               const ushort* __restrict__ chkbase, const float* __restrict__ cw2,
               const float* __restrict__ cb2v, const float* __restrict__ checked,
               const float* __restrict__ yv, float* __restrict__ logits,
               float* __restrict__ chkdotP, uint* __restrict__ counter,
               float* __restrict__ accv, int t)
{
  const int bx = blockIdx.x & 3;
  const int by = blockIdx.x >> 2;
  const int bm = by<<7, bn = bx<<7;
  const int tid = threadIdx.x;
  const int w = tid>>6, lane = tid&63;
  const int wm = (w>>1)<<6, wn = (w&1)<<6;
  const int rs = tid>>1;
  const int kh = (tid&1)<<5;
  const int l15 = lane&15, l4 = lane>>4;
  __shared__ ushort lsA[8192];
  __shared__ ushort lsB[8192];
  __shared__ float credc[2][128];
  __shared__ float red[256];
  __shared__ float bmx[32], bsm[32];
  __shared__ uint slastS;
  f32x4 acc[4][4];
  #pragma unroll
  for (int i=0;i<4;++i)
    #pragma unroll
    for (int jj=0;jj<4;++jj) acc[i][jj] = 0.f;

  const ushort* pa = h2 + (size_t)(bm+rs)*512 + kh;
  const ushort* pb = Wc + (size_t)(bn+rs)*512 + kh;
  uint4 va[4], vb[4];
  #pragma unroll
  for (int i=0;i<4;++i){ va[i] = *(const uint4*)(pa + i*8); vb[i] = *(const uint4*)(pb + i*8); }
  for (int kt=0; kt<8; ++kt){
    __syncthreads();
    #pragma unroll
    for (int i=0;i<4;++i){
      const int c = ((tid&1)<<2) + i;
      *(uint4*)&lsA[(size_t)((c<<7) + rs)<<3] = va[i];
      *(uint4*)&lsB[(size_t)((c<<7) + rs)<<3] = vb[i];
    }
    __syncthreads();
    if (kt < 7){
      const ushort* qa = pa + (size_t)(kt+1)*64;
      const ushort* qb = pb + (size_t)(kt+1)*64;
      #pragma unroll
      for (int i=0;i<4;++i){ va[i] = *(const uint4*)(qa + i*8); vb[i] = *(const uint4*)(qb + i*8); }
    }
    #pragma unroll
    for (int ks=0;ks<2;++ks){
      const int ch = (ks<<2) + l4;
      short8 af[4], bf[4];
      #pragma unroll
      for (int mi=0;mi<4;++mi) af[mi] = *(const short8*)&lsA[(size_t)((ch<<7) + wm + (mi<<4) + l15)<<3];
      #pragma unroll
      for (int ni=0;ni<4;++ni) bf[ni] = *(const short8*)&lsB[(size_t)((ch<<7) + wn + (ni<<4) + l15)<<3];
      #pragma unroll
      for (int mi=0;mi<4;++mi)
        #pragma unroll
        for (int ni=0;ni<4;++ni)
          acc[mi][ni] = __builtin_amdgcn_mfma_f32_16x16x32_bf16(af[mi], bf[ni], acc[mi][ni], 0,0,0);
    }
  }
  // epilogue: u = acc + chkbase ; rsum = sum over cols of tanh(u)*cw2[col]
  float rsum[4][4];
  #pragma unroll
  for (int mi=0;mi<4;++mi)
    #pragma unroll
    for (int q=0;q<4;++q) rsum[mi][q] = 0.f;
  #pragma unroll
  for (int mi=0;mi<4;++mi){
    #pragma unroll
    for (int ni=0;ni<4;++ni){
      const int col = bn + wn + (ni<<4) + l15;
      const float w2v = cw2[col];
      const int row0 = bm + wm + (mi<<4) + (l4<<2);
      #pragma unroll
      for (int q=0;q<4;++q){
        const float u = acc[mi][ni][q] + b2f(chkbase[(size_t)(row0+q)*H_ + col]);
        rsum[mi][q] += tanh_fast(u) * w2v;
      }
    }
  }
  #pragma unroll
  for (int mi=0;mi<4;++mi)
    #pragma unroll
    for (int q=0;q<4;++q){
      float v = rsum[mi][q];
      v += __shfl_xor(v,1); v += __shfl_xor(v,2); v += __shfl_xor(v,4); v += __shfl_xor(v,8);
      if (l15==0) credc[w&1][wm + (mi<<4) + (l4<<2) + q] = v;
    }
  __syncthreads();
  if (tid < 128) stf_sc1(chkdotP + bx*8192 + bm + tid, credc[0][tid] + credc[1][tid]);
  __syncthreads();   // drain sc1 stores before counter bump
  if (tid==0) slastS = atomicAdd(counter, 1u);
  __syncthreads();
  if (slastS != 255u) return;

  // ---------- losses (elected last block) ----------
  // chk loss
  float wsum = 0.f;
  {
    const float b2v = cb2v[0];
    const int r0 = tid*32;
    #pragma unroll
    for (int c=0;c<2;++c){
      float a0[16], a1[16], a2[16], a3[16];
      ld16_sc1(chkdotP + 0*8192 + r0 + c*16, a0);
      ld16_sc1(chkdotP + 1*8192 + r0 + c*16, a1);
      ld16_sc1(chkdotP + 2*8192 + r0 + c*16, a2);
      ld16_sc1(chkdotP + 3*8192 + r0 + c*16, a3);
      #pragma unroll
      for (int i=0;i<16;++i){
        const int row = r0 + c*16 + i, bb = row>>8, yy = row&255;
        const float u = a0[i]+a1[i]+a2[i]+a3[i] + b2v;
        const float cc = checked[((size_t)bb*33 + t + 1)*Y_ + yy];
        const float yt = yv[((size_t)bb*SOUT_ + t)*Y_ + yy];
        wsum += yt * (cc*splus(-u) + (1.f-cc)*splus(u));
      }
    }
  }
  red[tid] = wsum; __syncthreads();
  for (int o=128;o;o>>=1){ if (tid<o) red[tid] += red[tid+o]; __syncthreads(); }
  if (tid==0) atomicAdd(accv+1, red[0]);
  __syncthreads();
  // logit softmax loss (logits complete: written by gemm_dec of this step, earlier launch)
  {
    const int bb = tid>>3, part = tid&7;
    float lv[32];
    const float* lg = logits + bb*Y_ + part*32;
    float m = -1e30f;
    #pragma unroll
    for (int i=0;i<32;++i){ lv[i] = lg[i]; m = fmaxf(m, lv[i]); }
    red[tid] = m; __syncthreads();
    if (part==0){ float mm = red[tid];
      #pragma unroll
      for (int k2=1;k2<8;++k2) mm = fmaxf(mm, red[tid+k2]);
      bmx[bb] = mm; }
    __syncthreads();
    const float bmv = bmx[bb];
    float se = 0.f;
    #pragma unroll
    for (int i=0;i<32;++i) se += __expf(lv[i]-bmv);
    red[tid] = se; __syncthreads();
    if (part==0){ float ss = 0.f;
      #pragma unroll
      for (int k2=0;k2<8;++k2) ss += red[tid+k2];
      bsm[bb] = ss; }
    __syncthreads();
    const float lse = bmv + logf(bsm[bb]);
    const float* yr = yv + ((size_t)bb*SOUT_ + t)*Y_ + part*32;
    float pl = 0.f;
    #pragma unroll
    for (int i=0;i<32;++i) pl += yr[i]*(lv[i]-lse);
    red[tid] = pl; __syncthreads();
    if (tid==0){ float s = 0.f;
      for (int k2=0;k2<256;++k2) s += red[k2];
      atomicAdd(accv+0, -s); }
  }
  __syncthreads();
  // reset for next step (plain stores; visible next launch via kernel boundary — R4-proven)
  for (int i=tid; i<8192; i+=256) logits[i] = 0.f;
  if (tid==0) counter[0] = 0u;
}

__global__ void k_final(const float* __restrict__ acc, float* __restrict__ out)
{
  if (threadIdx.x==0){
    const float ls = acc[0], cls = acc[1], ys = acc[2];
    out[0] = (ls+cls)/ys; out[1] = ls/ys; out[2] = cls/ys;
  }
}

// ---------------- host ----------------
extern "C" void kernel_launch(void* const* d_in, const int* in_sizes, int n_in,
                              void* d_out, int out_size, void* d_ws, size_t ws_size,
                              hipStream_t stream)
{
  (void)in_sizes; (void)n_in; (void)out_size;
  const int*   x      = (const int*)d_in[0];
  const int*   akey   = (const int*)d_in[1];
  const int*   atype  = (const int*)d_in[2];
  const int*   croom  = (const int*)d_in[3];
  const float* checked= (const float*)d_in[4];
  const float* yv     = (const float*)d_in[5];
  const float* emb    = (const float*)d_in[6];
  const float* attab  = (const float*)d_in[7];
  const float* eWihF  = (const float*)d_in[8];
  const float* eWhhF  = (const float*)d_in[9];
  const float* ebihF  = (const float*)d_in[10];
  const float* ebhhF  = (const float*)d_in[11];
  const float* eWihB  = (const float*)d_in[12];
  const float* eWhhB  = (const float*)d_in[13];
  const float* ebihB  = (const float*)d_in[14];
  const float* ebhhB  = (const float*)d_in[15];
  const float* transW = (const float*)d_in[16];
  const float* transb = (const float*)d_in[17];
  const float* mergeW = (const float*)d_in[18];
  const float* mergeb = (const float*)d_in[19];
  const float* dWih   = (const float*)d_in[20];
  const float* dWhh   = (const float*)d_in[21];
  const float* dbih   = (const float*)d_in[22];
  const float* dbhh   = (const float*)d_in[23];
  const float* dW     = (const float*)d_in[24];
  const float* cW1    = (const float*)d_in[26];
  const float* cb1    = (const float*)d_in[27];
  const float* cW2    = (const float*)d_in[28];
  const float* cb2    = (const float*)d_in[29];

  char* base = (char*)d_ws;
  size_t off = 0;
  auto alloc = [&](size_t bytes)->char*{ char* p = base + off; off += (bytes + 255) & ~(size_t)255; return p; };

  float*  accv   = (float*)alloc(256);
  ushort* embxs  = (ushort*)alloc((size_t)SIN_*B_*E_*2);
  ushort* aemb   = (ushort*)alloc((size_t)Y_*E_*2);
  ushort* aembT  = (ushort*)alloc((size_t)Y_*E_*2);
  float*  avec   = (float*)alloc((size_t)Y_*32*4);
  ushort* yprev  = (ushort*)alloc((size_t)SOUT_*B_*Y_*2);
  ushort* acat   = (ushort*)alloc((size_t)SOUT_*B_*512*2);
  ushort* gi_fb  = (ushort*)alloc((size_t)2*SIN_*B_*TH_*2);
  ushort* gi_f   = gi_fb;
  ushort* gi_b   = gi_fb + (size_t)SIN_*B_*TH_;
  ushort* gibase = gi_fb;
  ushort* encout = (ushort*)alloc((size_t)B_*SIN_*1024*2);
  ushort* encoutT= (ushort*)alloc((size_t)B_*1024*SIN_*2);
  float*  hTf    = (float*)alloc((size_t)B_*H_*4);
  float*  hTb    = (float*)alloc((size_t)B_*H_*4);
  float*  h0dec  = (float*)alloc((size_t)B_*H_*4);
  ushort* esum   = (ushort*)alloc((size_t)B_*SIN_*E_*2);
  float*  scores = (float*)alloc((size_t)B_*Y_*SIN_*4);
  ushort* alpha  = (ushort*)alloc((size_t)B_*Y_*SIN_*2);
  ushort* att    = (ushort*)alloc((size_t)8192*1024*2);
  ushort* chkbase= (ushort*)alloc((size_t)8192*H_*2);
  float*  addy   = (float*)alloc((size_t)Y_*TH_*4);
  float*  addcy  = (float*)alloc((size_t)Y_*H_*4);
  float*  sproj  = (float*)alloc((size_t)SOUT_*B_*TH_*4);
  float*  wchk   = (float*)alloc((size_t)TH_*4);
  float*  dbhhrz = (float*)alloc((size_t)TH_*4);
  ushort* WihFb  = (ushort*)alloc((size_t)TH_*E_*2);
  ushort* WihBb  = (ushort*)alloc((size_t)TH_*E_*2);
  ushort* Wtrb   = (ushort*)alloc((size_t)E_*1024*2);
  ushort* Wattb  = (ushort*)alloc((size_t)TH_*1024*2);
  ushort* Wcat2b = (ushort*)alloc((size_t)TH_*512*2);
  ushort* W1attb = (ushort*)alloc((size_t)H_*1024*2);
  ushort* Wdecb  = (ushort*)alloc((size_t)TH_*512*2);
  ushort* Wchk2b = (ushort*)alloc((size_t)512*512*2);
  ushort* h2bA   = (ushort*)alloc((size_t)8192*H_*2);
  ushort* h2bB   = (ushort*)alloc((size_t)8192*H_*2);
  float*  chkdotP= (float*)alloc((size_t)4*8192*4);
  float*  logits = (float*)alloc((size_t)8192*4);
  ushort* hG     = (ushort*)alloc((size_t)2*2*32*512*2);
  uint*   flags  = (uint*)alloc((size_t)256*4);
  uint*   counter= (uint*)alloc((size_t)256);

  if (off > ws_size){ k_wsfail<<<1,1,0,stream>>>((float*)d_out); return; }

  float* outp = (float*)d_out;

  k_init<<<dim3(1), dim3(64), 0, stream>>>(accv);
  k_init_enc<<<dim3(64), dim3(256), 0, stream>>>(flags, hG);
  k_ysum<<<dim3(256), dim3(256), 0, stream>>>(yv, accv);
  k_lookup<<<dim3(2048), dim3(256), 0, stream>>>(x, akey, atype, croom, yv, emb, attab,
                                                 embxs, aemb, aembT, avec, acat, yprev);
  k_convall<<<dim3(2048), dim3(256), 0, stream>>>(eWihF, eWihB, transW, dWih, cW1, dWhh,
                                                  WihFb, WihBb, Wtrb, Wattb, Wcat2b, W1attb, Wdecb, Wchk2b);
  k_prep2<<<dim3(1024), dim3(256), 0, stream>>>(avec, dWih, dbih, cW1, cb1, dbhh,
                                                addy, addcy, wchk, dbhhrz);

  // encoder input projections (bias folded in)
  gemm_nt<(GF_BIAS|GF_WBF16)><<<dim3(12,32,1), dim3(256), 0, stream>>>(
    embxs, WihFb, ebihF, nullptr, 0, nullptr, gi_f, TH_, E_, E_, E_, 0, 0L,0L,0L, nullptr);
  gemm_nt<(GF_BIAS|GF_WBF16)><<<dim3(12,32,1), dim3(256), 0, stream>>>(
    embxs, WihBb, ebihB, nullptr, 0, nullptr, gi_b, TH_, E_, E_, E_, 0, 0L,0L,0L, nullptr);

  enc_persist<<<dim3(64), dim3(256), 0, stream>>>(eWhhF, eWhhB, ebhhF, ebhhB, gi_f, gi_b,
                                                  hG, flags, encout, encoutT, hTf, hTb);

  // esum = bf16( tanh(enc_out @ trans_W^T + b) + emb )
  gemm_nt<(GF_BIAS|GF_TANH|GF_ESUM|GF_WBF16)><<<dim3(2,32,1), dim3(256), 0, stream>>>(
    encout, Wtrb, transb, nullptr, 0, nullptr, esum, E_, 1024, 1024, 1024, 0, 0L,0L,0L, embxs);

  // scores[b] = action_emb @ embsum_b^T
  gemm_nt<GF_WF32><<<dim3(1,2,32), dim3(256), 0, stream>>>(
    aemb, esum, nullptr, nullptr, 0, scores, nullptr, SIN_, E_, E_, E_, 0,
    0L, (long)SIN_*E_, (long)Y_*SIN_, nullptr);
  k_softmax<<<dim3(2048), dim3(256), 0, stream>>>(scores, alpha);

  // attention[b] = alpha_b @ enc_out_b
  gemm_nt<GF_WBF16><<<dim3(8,2,32), dim3(256), 0, stream>>>(
    alpha, encoutT, nullptr, nullptr, 0, nullptr, att, 1024, SIN_, SIN_, SIN_, 0,
    (long)Y_*SIN_, (long)1024*SIN_, (long)Y_*1024, nullptr);

  k_merge<<<dim3(32), dim3(512), 0, stream>>>(hTf, hTb, mergeW, mergeb, h0dec);

  // yemb -> acat[:,256:512]
  gemm_nt<GF_WBF16><<<dim3(2,8,1), dim3(256), 0, stream>>>(
    yprev, aembT, nullptr, nullptr, 0, nullptr, acat+256, 512, Y_, Y_, Y_, 0, 0L,0L,0L, nullptr);
  // sproj = acat @ Wcat2^T + dbhh_rz
  gemm_nt<(GF_BIAS|GF_WF32)><<<dim3(12,8,1), dim3(256), 0, stream>>>(
    acat, Wcat2b, dbhhrz, nullptr, 0, sproj, nullptr, TH_, 512, 512, 512, 0, 0L,0L,0L, nullptr);

  // gi_base = att @ W_att^T + add_y[y]   ;  chk_base = att @ W1_att^T + addc_y[y]
  gemm_nt<(GF_WBF16|GF_ADDY)><<<dim3(12,64,1), dim3(256), 0, stream>>>(
    att, Wattb, nullptr, addy, TH_, nullptr, gibase, TH_, 1024, 1024, 1024, 0, 0L,0L,0L, nullptr);
  gemm_nt<(GF_WBF16|GF_ADDY)><<<dim3(4,64,1), dim3(256), 0, stream>>>(
    att, W1attb, nullptr, addcy, H_, nullptr, chkbase, H_, 1024, 1024, 1024, 0, 0L,0L,0L, nullptr);

  k_bcast<<<dim3(4096), dim3(256), 0, stream>>>(h0dec, h2bA, logits, counter);

  for (int t=0; t<SOUT_; ++t){
    const ushort* hin = (t&1) ? h2bB : h2bA;
    ushort* hout      = (t&1) ? h2bA : h2bB;
    gemm_dec<<<dim3(4,64), dim3(512), 0, stream>>>(
      hin, Wdecb, gibase, sproj + (size_t)t*B_*TH_, wchk, dbhh, checked, t,
      dW, hout, logits);
    chk_fused<<<dim3(256), dim3(256), 0, stream>>>(
      hout, Wchk2b, chkbase, cW2, cb2, checked, yv, logits, chkdotP, counter, accv, t);
  }
  k_final<<<dim3(1), dim3(1), 0, stream>>>(accv, outp);
}

// Round 7
// 3934.932 us; speedup vs baseline: 1.6922x; 1.2567x over previous
//
#include <hip/hip_runtime.h>

typedef unsigned short ushort;
typedef unsigned int uint;
typedef __attribute__((ext_vector_type(8))) short short8;
typedef __attribute__((ext_vector_type(4))) float f32x4;
typedef __attribute__((ext_vector_type(4))) uint u32x4;

#define DEVI __device__ __forceinline__

#define B_ 32
#define SIN_ 128
#define SOUT_ 32
#define Y_ 256
#define H_ 512
#define E_ 256
#define TH_ 1536

DEVI float b2f(ushort u){ return __uint_as_float(((uint)u)<<16); }
DEVI ushort f2b(float f){ uint x = __float_as_uint(f); return (ushort)((x + 0x7FFFu + ((x>>16)&1u)) >> 16); }
DEVI float sigf(float x){ return 1.f/(1.f+__expf(-x)); }
DEVI float tanh_fast(float x){ return 2.f/(1.f+__expf(-2.f*x)) - 1.f; }
DEVI float splus(float x){ return fmaxf(x,0.f) + log1pf(__expf(-fabsf(x))); }
DEVI short8 cvt8(u32x4 v){ return __builtin_bit_cast(short8, v); }

// sc0 sc1 = coherent through Infinity Cache (cross-XCD visible without fences)
DEVI uint ld_flag(const uint* p){
  uint r;
  asm volatile("global_load_dword %0, %1, off sc0 sc1\n\ts_waitcnt vmcnt(0)"
               : "=v"(r) : "v"(p) : "memory");
  return r;
}
DEVI void st_flag(uint* p, uint v){
  asm volatile("global_store_dword %0, %1, off sc0 sc1" :: "v"(p), "v"(v) : "memory");
}
DEVI void st_h16(ushort* p, uint v){
  asm volatile("global_store_short %0, %1, off sc0 sc1" :: "v"(p), "v"(v) : "memory");
}

// ---------------- init / reductions ----------------
__global__ void k_init(float* acc){ if (threadIdx.x < 4) acc[threadIdx.x] = 0.f; }

__global__ void k_wsfail(float* out){ out[0]=1.2345e8f; out[1]=2.3456e8f; out[2]=3.4567e8f; }

__global__ void k_init_enc(uint* __restrict__ flags, ushort* __restrict__ hG)
{
  const int id = blockIdx.x*256 + threadIdx.x;
  if (id < 256) flags[id] = 0u;
  if (id < 8192) ((uint4*)hG)[id] = make_uint4(0,0,0,0);
}

__global__ __launch_bounds__(256) void k_ysum(const float* __restrict__ yv, float* __restrict__ acc)
{
  __shared__ float red[256];
  float s = 0.f;
  for (long i = (long)blockIdx.x*256 + threadIdx.x; i < (long)B_*SOUT_*Y_; i += (long)gridDim.x*256) s += yv[i];
  red[threadIdx.x] = s; __syncthreads();
  for (int o=128;o;o>>=1){ if ((int)threadIdx.x<o) red[threadIdx.x] += red[threadIdx.x+o]; __syncthreads(); }
  if (threadIdx.x==0) atomicAdd(acc+2, red[0]);
}

// ---------------- embedding / lookup ----------------
__global__ void k_lookup(const int* __restrict__ x, const int* __restrict__ akey,
                         const int* __restrict__ atype, const int* __restrict__ croom,
                         const float* __restrict__ yv,
                         const float* __restrict__ emb, const float* __restrict__ attab,
                         ushort* __restrict__ embxs, ushort* __restrict__ aemb,
                         ushort* __restrict__ aembT, float* __restrict__ avec,
                         ushort* __restrict__ acat, ushort* __restrict__ yprev)
{
  const long N1 = (long)SIN_*B_*E_;
  const long N2 = (long)Y_*E_;
  const long N3 = (long)Y_*32;
  const long N4 = (long)SOUT_*B_*E_;
  const long N5 = (long)SOUT_*B_*Y_;
  for (long i = (long)blockIdx.x*blockDim.x + threadIdx.x; i < N1+N2+N3+N4+N5; i += (long)gridDim.x*blockDim.x){
    long id = i;
    if (id < N1){
      int e = id & 255; long sb = id >> 8; int bb = (int)(sb & 31); int s = (int)(sb >> 5);
      embxs[id] = f2b(emb[(size_t)x[bb*SIN_ + s]*E_ + e]);
    } else if ((id -= N1) < N2){
      int e = (int)(id & 255), yy = (int)(id >> 8);
      ushort v = f2b(emb[(size_t)akey[yy]*E_ + e]);
      aemb[yy*E_ + e] = v;
      aembT[e*Y_ + yy] = v;
    } else if ((id -= N2) < N3){
      int a = (int)(id & 31), yy = (int)(id >> 5);
      avec[yy*32 + a] = attab[atype[yy]*32 + a];
    } else if ((id -= N3) < N4){
      int e = (int)(id & 255); long tb = id >> 8; int bb = (int)(tb & 31); int t = (int)(tb >> 5);
      acat[(size_t)tb*512 + e] = f2b(emb[(size_t)croom[bb*SOUT_ + t]*E_ + e]);
    } else { id -= N4;
      int yy = (int)(id & 255); long tb = id >> 8; int bb = (int)(tb & 31); int t = (int)(tb >> 5);
      yprev[id] = (t == 0) ? (ushort)0 : f2b(yv[((size_t)bb*SOUT_ + (t-1))*Y_ + yy]);
    }
  }
}

// all f32->bf16 weight conversions in one kernel
__global__ __launch_bounds__(256)
void k_convall(const float* __restrict__ eWihF, const float* __restrict__ eWihB,
               const float* __restrict__ transW, const float* __restrict__ dWih,
               const float* __restrict__ cW1, const float* __restrict__ dWhh,
               ushort* __restrict__ WihFb, ushort* __restrict__ WihBb,
               ushort* __restrict__ Wtrb, ushort* __restrict__ Wattb,
               ushort* __restrict__ Wcat2b, ushort* __restrict__ W1attb,
               ushort* __restrict__ Wdecb, ushort* __restrict__ Wchk2b)
{
  const long N1 = 393216;
  const long N2 = 393216;
  const long N3 = 262144;
  const long N4 = 1572864;
  const long N5 = 393216;
  const long N6 = 393216;
  const long N7 = 524288;
  const long N8 = 786432;
  const long N9 = 262144;
  const long NT = N1+N2+N3+N4+N5+N6+N7+N8+N9;
  for (long i = (long)blockIdx.x*256 + threadIdx.x; i < NT; i += (long)gridDim.x*256){
    long id = i;
    if (id < N1){ WihFb[id] = f2b(eWihF[id]); }
    else if ((id -= N1) < N2){ WihBb[id] = f2b(eWihB[id]); }
    else if ((id -= N2) < N3){ Wtrb[id] = f2b(transW[id]); }
    else if ((id -= N3) < N4){
      const long r = id>>10, c = id&1023;
      Wattb[id] = f2b(dWih[r*1569 + c]);
    }
    else if ((id -= N4) < N5){
      const long r = id>>8, c = id&255;
      Wcat2b[r*512 + c] = f2b(dWih[r*1569 + 1025 + c]);
    }
    else if ((id -= N5) < N6){
      const long r = id>>8, c = id&255;
      Wcat2b[r*512 + 256 + c] = f2b(dWih[r*1569 + 1313 + c]);
    }
    else if ((id -= N6) < N7){
      const long r = id>>10, c = id&1023;
      W1attb[id] = f2b(cW1[r*1568 + c]);
    }
    else if ((id -= N7) < N8){ Wdecb[id] = f2b(dWhh[id]); }
    else { id -= N8;
      const long r = id>>9, c = id&511;
      Wchk2b[id] = f2b(cW1[r*1568 + 1056 + c]);
    }
  }
}

// add_y, addc_y, wchk, dbhh_rz
__global__ void k_prep2(const float* __restrict__ avec, const float* __restrict__ decWih,
                        const float* __restrict__ dbih, const float* __restrict__ cW1,
                        const float* __restrict__ cb1, const float* __restrict__ dbhh,
                        float* __restrict__ addy, float* __restrict__ addcy,
                        float* __restrict__ wchk, float* __restrict__ dbhhrz)
{
  const long NA = (long)Y_*TH_;
  const long NB = (long)Y_*H_;
  for (long i = (long)blockIdx.x*blockDim.x + threadIdx.x; i < NA+NB+TH_+TH_; i += (long)gridDim.x*blockDim.x){
    long id = i;
    if (id < NA){
      int n = (int)(id % TH_), yy = (int)(id / TH_);
      float s = dbih[n];
      const float* wr = decWih + (size_t)n*1569 + 1281;
      const float* av = avec + yy*32;
      #pragma unroll
      for (int a=0;a<32;++a) s += av[a]*wr[a];
      addy[id] = s;
    } else if ((id -= NA) < NB){
      int n = (int)(id & 511), yy = (int)(id >> 9);
      float s = cb1[n];
      const float* wr = cW1 + (size_t)n*1568 + 1024;
      const float* av = avec + yy*32;
      #pragma unroll
      for (int a=0;a<32;++a) s += av[a]*wr[a];
      addcy[id] = s;
    } else if ((id -= NB) < TH_){
      wchk[id] = decWih[(size_t)id*1569 + 1024];
    } else { id -= TH_;
      dbhhrz[id] = (id < 1024) ? dbhh[id] : 0.f;
    }
  }
}

// ---------------- bf16 NT GEMM: C[M,N] = A[M,K] @ W[N,K]^T  (MFMA 16x16x32) ----------------
#define GF_BIAS 1
#define GF_TANH 2
#define GF_WF32 4
#define GF_WBF16 8
#define GF_ADDY 32
#define GF_CHK 64
#define GF_ESUM 128

template<int FLAGS>
__global__ __launch_bounds__(256)
void gemm_nt(const ushort* __restrict__ A, const ushort* __restrict__ W,
             const float* __restrict__ bias,
             const float* __restrict__ addy, int lday,
             float* __restrict__ Cf, ushort* __restrict__ Cb, int ldC,
             int K, int ldA, int ldW, int n0,
             long zA, long zW, long zC,
             const ushort* __restrict__ chkbase)
{
  const int z = blockIdx.z;
  A += (long)z*zA; W += (long)z*zW;
  const int bn = n0 + (blockIdx.x<<7);
  const int bm = (blockIdx.y<<7);
  const int tid = threadIdx.x;
  const int w = tid>>6, lane = tid&63;
  const int wm = (w>>1)<<6, wn = (w&1)<<6;
  const int rs = tid>>1;
  const int kh = (tid&1)<<5;
  __shared__ ushort lsA[8192];
  __shared__ ushort lsB[8192];
  f32x4 acc[4][4];
  #pragma unroll
  for (int i=0;i<4;++i)
    #pragma unroll
    for (int jj=0;jj<4;++jj) acc[i][jj] = 0.f;

  const ushort* pa = A + (size_t)(bm+rs)*ldA + kh;
  const ushort* pb = W + (size_t)(bn+rs)*ldW + kh;
  uint4 va[4], vb[4];
  #pragma unroll
  for (int i=0;i<4;++i){ va[i] = *(const uint4*)(pa + i*8); vb[i] = *(const uint4*)(pb + i*8); }
  const int nkt = K>>6;
  for (int kt=0; kt<nkt; ++kt){
    __syncthreads();
    #pragma unroll
    for (int i=0;i<4;++i){
      const int c = ((tid&1)<<2) + i;
      *(uint4*)&lsA[(size_t)((c<<7) + rs)<<3] = va[i];
      *(uint4*)&lsB[(size_t)((c<<7) + rs)<<3] = vb[i];
    }
    __syncthreads();
    if (kt+1 < nkt){
      const ushort* qa = pa + (size_t)(kt+1)*64;
      const ushort* qb = pb + (size_t)(kt+1)*64;
      #pragma unroll
      for (int i=0;i<4;++i){ va[i] = *(const uint4*)(qa + i*8); vb[i] = *(const uint4*)(qb + i*8); }
    }
    #pragma unroll
    for (int ks=0;ks<2;++ks){
      const int ch = (ks<<2) + (lane>>4);
      short8 af[4], bf[4];
      #pragma unroll
      for (int mi=0;mi<4;++mi) af[mi] = *(const short8*)&lsA[(size_t)((ch<<7) + wm + (mi<<4) + (lane&15))<<3];
      #pragma unroll
      for (int ni=0;ni<4;++ni) bf[ni] = *(const short8*)&lsB[(size_t)((ch<<7) + wn + (ni<<4) + (lane&15))<<3];
      #pragma unroll
      for (int mi=0;mi<4;++mi)
        #pragma unroll
        for (int ni=0;ni<4;++ni)
          acc[mi][ni] = __builtin_amdgcn_mfma_f32_16x16x32_bf16(af[mi], bf[ni], acc[mi][ni], 0,0,0);
    }
  }
  if (FLAGS & GF_CHK){
    // chk MLP: u = acc + chkbase ; accumulate tanh(u)*cW2[col] into chkdot[row] (Cf)
    float rsum[4][4];
    #pragma unroll
    for (int mi=0;mi<4;++mi)
      #pragma unroll
      for (int q=0;q<4;++q) rsum[mi][q] = 0.f;
    #pragma unroll
    for (int mi=0;mi<4;++mi){
      #pragma unroll
      for (int ni=0;ni<4;++ni){
        const int col = bn + wn + (ni<<4) + (lane&15);
        const float w2v = addy[col];
        const int row0 = bm + wm + (mi<<4) + ((lane>>4)<<2);
        #pragma unroll
        for (int q=0;q<4;++q){
          const float u = acc[mi][ni][q] + b2f(chkbase[(size_t)(row0+q)*H_ + col]);
          rsum[mi][q] += tanh_fast(u) * w2v;
        }
      }
    }
    #pragma unroll
    for (int mi=0;mi<4;++mi)
      #pragma unroll
      for (int q=0;q<4;++q){
        float v = rsum[mi][q];
        v += __shfl_xor(v,1); v += __shfl_xor(v,2); v += __shfl_xor(v,4); v += __shfl_xor(v,8);
        if ((lane&15)==0){
          const int row = bm + wm + (mi<<4) + ((lane>>4)<<2) + q;
          atomicAdd(&Cf[row], v);
        }
      }
  } else {
    const long zc = (long)z*zC;
    #pragma unroll
    for (int mi=0;mi<4;++mi){
      #pragma unroll
      for (int ni=0;ni<4;++ni){
        const int col = bn + wn + (ni<<4) + (lane&15);
        const int row0 = bm + wm + (mi<<4) + ((lane>>4)<<2);
        float bv = 0.f;
        if (FLAGS & GF_BIAS) bv = bias[col];
        #pragma unroll
        for (int q=0;q<4;++q){
          const int row = row0 + q;
          float xv = acc[mi][ni][q] + bv;
          if (FLAGS & GF_ADDY) xv += addy[(size_t)(row&255)*lday + col];
          if (FLAGS & GF_TANH) xv = tanh_fast(xv);
          if (FLAGS & GF_ESUM) xv += b2f(chkbase[((size_t)(row&127)*32 + (row>>7))*256 + col]);
          if (FLAGS & GF_WF32)  Cf[zc + (size_t)row*ldC + col] = xv;
          if (FLAGS & GF_WBF16) Cb[zc + (size_t)row*ldC + col] = f2b(xv);
        }
      }
    }
  }
}

// ---------------- persistent bi-GRU encoder (fence-free sc1 exchange, hi-only bf16 h) ----------------
__global__ __launch_bounds__(256,1)
void enc_persist(const float* __restrict__ Wf, const float* __restrict__ Wb,
                 const float* __restrict__ bhf, const float* __restrict__ bhb,
                 const ushort* __restrict__ gif, const ushort* __restrict__ gib,
                 ushort* __restrict__ hG, uint* __restrict__ flags,
                 ushort* __restrict__ encout, ushort* __restrict__ encoutT,
                 float* __restrict__ hTf, float* __restrict__ hTb)
{
  const int g = blockIdx.x;
  const int dir = g >> 5;
  const int j0 = (g & 31) << 4;
  const int tid = threadIdx.x;
  const int w = tid >> 6, lane = tid & 63;
  const int mi = w & 1, kh = w >> 1;
  const int l15 = lane & 15, l4 = lane >> 4;
  const int brow0 = mi*16 + l4*4;

  const float* W = dir ? Wb : Wf;
  const float* bh = dir ? bhb : bhf;
  const ushort* gi = dir ? gib : gif;

  __shared__ __align__(16) float cred[2][3][256];
  __shared__ float bhl[48];

  short8 bw[3][8];
  {
    const int kbase = kh*256 + l4*8;
    #pragma unroll
    for (int ni=0; ni<3; ++ni){
      const float* wr = W + (size_t)(ni*512 + j0 + l15)*512 + kbase;
      #pragma unroll
      for (int ks=0; ks<8; ++ks){
        const float4 f0 = *(const float4*)(wr + ks*32);
        const float4 f1 = *(const float4*)(wr + ks*32 + 4);
        short8 v;
        v[0]=(short)f2b(f0.x); v[1]=(short)f2b(f0.y); v[2]=(short)f2b(f0.z); v[3]=(short)f2b(f0.w);
        v[4]=(short)f2b(f1.x); v[5]=(short)f2b(f1.y); v[6]=(short)f2b(f1.z); v[7]=(short)f2b(f1.w);
        bw[ni][ks] = v;
      }
    }
  }
  if (tid < 48) bhl[tid] = bh[(tid>>4)*512 + j0 + (tid&15)];
  __syncthreads();

  float bh0r=0.f, bh1r=0.f, bh2r=0.f;
  if (kh==0){ bh0r = bhl[l15]; bh1r = bhl[16+l15]; bh2r = bhl[32+l15]; }
  float holdr[4] = {0.f,0.f,0.f,0.f};
  uint* myflag = flags + dir*32 + (g&31);

  for (int t=0; t<128; ++t){
    const int tt = dir ? (127 - t) : t;
    float giv0[4], giv1[4], giv2[4];
    if (kh==0){
      const ushort* girow = gi + ((size_t)tt*32 + brow0)*1536 + j0 + l15;
      #pragma unroll
      for (int q=0; q<4; ++q){
        giv0[q] = b2f(girow[q*1536]);
        giv1[q] = b2f(girow[q*1536 + 512]);
        giv2[q] = b2f(girow[q*1536 + 1024]);
      }
    }
    if (t){
      if ((tid>>6)==2 && (tid&63)<32){
        const uint* fp = flags + dir*32 + (tid&31);
        while (ld_flag(fp) < (uint)t) __builtin_amdgcn_s_sleep(2);
      }
      __syncthreads();
    }
    const ushort* hsrc = hG + ((size_t)((t&1)*2 + dir))*16384 + (size_t)(mi*16+l15)*512 + kh*256 + l4*8;
    u32x4 a0,a1,a2,a3,a4,a5,a6,a7;
    asm volatile(
      "global_load_dwordx4 %0, %8, off sc0 sc1\n\t"
      "global_load_dwordx4 %1, %8, off offset:64 sc0 sc1\n\t"
      "global_load_dwordx4 %2, %8, off offset:128 sc0 sc1\n\t"
      "global_load_dwordx4 %3, %8, off offset:192 sc0 sc1\n\t"
      "global_load_dwordx4 %4, %8, off offset:256 sc0 sc1\n\t"
      "global_load_dwordx4 %5, %8, off offset:320 sc0 sc1\n\t"
      "global_load_dwordx4 %6, %8, off offset:384 sc0 sc1\n\t"
      "global_load_dwordx4 %7, %8, off offset:448 sc0 sc1\n\t"
      "s_waitcnt vmcnt(0)"
      : "=&v"(a0),"=&v"(a1),"=&v"(a2),"=&v"(a3),"=&v"(a4),"=&v"(a5),"=&v"(a6),"=&v"(a7)
      : "v"(hsrc)
      : "memory");
    const short8 ah[8] = {cvt8(a0),cvt8(a1),cvt8(a2),cvt8(a3),cvt8(a4),cvt8(a5),cvt8(a6),cvt8(a7)};
    f32x4 acc[3]; acc[0]=0.f; acc[1]=0.f; acc[2]=0.f;
    #pragma unroll
    for (int ks=0; ks<8; ++ks){
      acc[0] = __builtin_amdgcn_mfma_f32_16x16x32_bf16(ah[ks], bw[0][ks], acc[0],0,0,0);
      acc[1] = __builtin_amdgcn_mfma_f32_16x16x32_bf16(ah[ks], bw[1][ks], acc[1],0,0,0);
      acc[2] = __builtin_amdgcn_mfma_f32_16x16x32_bf16(ah[ks], bw[2][ks], acc[2],0,0,0);
    }
    if (kh==1){
      #pragma unroll
      for (int ni=0; ni<3; ++ni) *(f32x4*)&cred[mi][ni][lane*4] = acc[ni];
    }
    __syncthreads();
    ushort hbs[4];
    if (kh==0){
      #pragma unroll
      for (int ni=0; ni<3; ++ni){
        const f32x4 o = *(const f32x4*)&cred[mi][ni][lane*4];
        acc[ni][0]+=o[0]; acc[ni][1]+=o[1]; acc[ni][2]+=o[2]; acc[ni][3]+=o[3];
      }
      ushort* dst = hG + ((size_t)(((t+1)&1)*2 + dir))*16384;
      #pragma unroll
      for (int q=0; q<4; ++q){
        const int b = brow0 + q;
        const float r  = sigf(giv0[q] + acc[0][q] + bh0r);
        const float zg = sigf(giv1[q] + acc[1][q] + bh1r);
        const float n  = tanh_fast(giv2[q] + r*(acc[2][q] + bh2r));
        const float h2 = (1.f - zg)*n + zg*holdr[q];
        holdr[q] = h2;
        const ushort hb = f2b(h2);
        hbs[q] = hb;
        if (t < 127) st_h16(dst + (size_t)b*512 + j0 + l15, (uint)hb);
      }
    }
    __syncthreads();   // drains kh==0 waves' sc1 h-stores before flag
    if (t < 127 && tid == 0) st_flag(myflag, (uint)(t+1));
    if (kh==0){
      #pragma unroll
      for (int q=0; q<4; ++q){
        const int b = brow0 + q;
        encout[((size_t)b*SIN_ + tt)*1024 + dir*H_ + j0 + l15] = hbs[q];
        encoutT[((size_t)b*1024 + dir*H_ + j0 + l15)*SIN_ + tt] = hbs[q];
      }
    }
  }
  if (kh==0){
    float* hT = dir ? hTb : hTf;
    #pragma unroll
    for (int q=0; q<4; ++q) hT[(size_t)(brow0+q)*H_ + j0 + l15] = holdr[q];
  }
}

// row softmax over SIN=128, one wave per row
__global__ __launch_bounds__(256) void k_softmax(const float* __restrict__ sc, ushort* __restrict__ al)
{
  const int row = blockIdx.x*4 + (threadIdx.x>>6);
  const int lane = threadIdx.x&63;
  const float* s = sc + (size_t)row*SIN_;
  const float2 v = *(const float2*)&s[lane*2];
  float m = fmaxf(v.x, v.y);
  #pragma unroll
  for (int o=1;o<64;o<<=1) m = fmaxf(m, __shfl_xor(m, o));
  const float e0 = __expf(v.x - m), e1 = __expf(v.y - m);
  float sum = e0 + e1;
  #pragma unroll
  for (int o=1;o<64;o<<=1) sum += __shfl_xor(sum, o);
  const float inv = 1.f/sum;
  ushort* a = al + (size_t)row*SIN_;
  const uint pkv = (uint)f2b(e0*inv) | ((uint)f2b(e1*inv)<<16);
  *(uint*)&a[lane*2] = pkv;
}

// h0_dec = tanh(hidden_cat @ merge_W^T + merge_b)
__global__ __launch_bounds__(512)
void k_merge(const float* __restrict__ hTf, const float* __restrict__ hTb,
             const float* __restrict__ mW, const float* __restrict__ mb,
             float* __restrict__ h0)
{
  const int b = blockIdx.x, j = threadIdx.x;
  __shared__ float hc[1024];
  for (int i=j; i<1024; i+=512){
    const int half = i >> 9, jj = i & 511;
    hc[i] = (b < 16) ? hTf[(size_t)(2*b + half)*H_ + jj] : hTb[(size_t)(2*(b-16) + half)*H_ + jj];
  }
  __syncthreads();
  float d = mb[j];
  const float* wr = mW + (size_t)j*1024;
  #pragma unroll 8
  for (int k=0;k<1024;k+=4){
    const float4 a = *(const float4*)&wr[k];
    const float4 hh = *(const float4*)&hc[k];
    d += a.x*hh.x + a.y*hh.y + a.z*hh.z + a.w*hh.w;
  }
  h0[(size_t)b*H_ + j] = tanh_fast(d);
}

__global__ void k_bcast(const float* __restrict__ h0, ushort* __restrict__ hb,
                        float* __restrict__ L0, float* __restrict__ L1,
                        float* __restrict__ C0, float* __restrict__ C1)
{
  for (long i = (long)blockIdx.x*blockDim.x + threadIdx.x; i < (long)8192*H_; i += (long)gridDim.x*blockDim.x){
    const int jj = (int)(i & 511); const long row = i >> 9; const int bb = (int)(row >> 8);
    hb[i] = f2b(h0[(size_t)bb*H_ + jj]);
    if (i < 8192){ L0[i] = 0.f; L1[i] = 0.f; C0[i] = 0.f; C1[i] = 0.f; }
  }
}

// ---------------- decoder step: dec GEMM+gates (blocks 0-255) + losses of step t-1 (blocks 256-272) ----------------
__global__ __launch_bounds__(512,1)
void gemm_dec2(const ushort* __restrict__ A, const ushort* __restrict__ Wd,
               const ushort* __restrict__ gib, const float* __restrict__ sproj_t,
               const float* __restrict__ wchk, const float* __restrict__ dbhh,
               const float* __restrict__ checked, int t,
               const float* __restrict__ decW,
               ushort* __restrict__ h2bo, float* __restrict__ LW,
               float* __restrict__ chkdotR, const float* __restrict__ cb2v,
               const float* __restrict__ yv, float* __restrict__ LR,
               float* __restrict__ accv)
{
  __shared__ __align__(16) ushort smem[36864];   // 72 KB: dec staging / loss scratch
  const int tid = threadIdx.x;

  if (blockIdx.x < 256){
    // ---------------- dec role (step t) ----------------
    if (t >= SOUT_) return;
    const int bx = blockIdx.x & 3;
    const int by = blockIdx.x >> 2;
    const int bm = by<<7;
    const int w = tid>>6, lane = tid&63;
    const int wrh = w>>2, wc = w&3;
    const int wm = wrh<<6;
    const int l15 = lane&15, l4 = lane>>4;
    ushort* lsA = smem;
    ushort* lsB = smem + 128*72;
    f32x4 acc[3][4][2];
    #pragma unroll
    for (int gg=0;gg<3;++gg)
      #pragma unroll
      for (int mi2=0;mi2<4;++mi2)
        #pragma unroll
        for (int ni2=0;ni2<2;++ni2) acc[gg][mi2][ni2] = 0.f;

    const int saRow0 = tid>>3, saK = (tid&7)<<3;
    uint4 va[2], vb[6];
    {
      #pragma unroll
      for (int i=0;i<2;++i){
        const int row = saRow0 + (i<<6);
        va[i] = *(const uint4*)&A[(size_t)(bm+row)*512 + saK];
      }
      #pragma unroll
      for (int i=0;i<6;++i){
        const int s = tid + (i<<9);
        const int gg = s>>10, w1 = s&1023, row = w1>>3, kc = (w1&7)<<3;
        vb[i] = *(const uint4*)&Wd[(size_t)((gg<<9) + (bx<<7) + row)*512 + kc];
      }
    }
    for (int kt=0; kt<8; ++kt){
      __syncthreads();
      #pragma unroll
      for (int i=0;i<2;++i){
        const int row = saRow0 + (i<<6);
        *(uint4*)&lsA[row*72 + saK] = va[i];
      }
      #pragma unroll
      for (int i=0;i<6;++i){
        const int s = tid + (i<<9);
        const int gg = s>>10, w1 = s&1023, row = w1>>3, kc = (w1&7)<<3;
        *(uint4*)&lsB[((gg<<7)+row)*72 + kc] = vb[i];
      }
      __syncthreads();
      if (kt < 7){
        const int ko = (kt+1)<<6;
        #pragma unroll
        for (int i=0;i<2;++i){
          const int row = saRow0 + (i<<6);
          va[i] = *(const uint4*)&A[(size_t)(bm+row)*512 + ko + saK];
        }
        #pragma unroll
        for (int i=0;i<6;++i){
          const int s = tid + (i<<9);
          const int gg = s>>10, w1 = s&1023, row = w1>>3, kc = (w1&7)<<3;
          vb[i] = *(const uint4*)&Wd[(size_t)((gg<<9) + (bx<<7) + row)*512 + ko + kc];
        }
      }
      #pragma unroll
      for (int ks=0;ks<2;++ks){
        short8 af[4];
        #pragma unroll
        for (int mi2=0;mi2<4;++mi2)
          af[mi2] = *(const short8*)&lsA[(wm + (mi2<<4) + l15)*72 + (ks<<5) + (l4<<3)];
        short8 bf[3][2];
        #pragma unroll
        for (int gg=0;gg<3;++gg)
          #pragma unroll
          for (int ni2=0;ni2<2;++ni2)
            bf[gg][ni2] = *(const short8*)&lsB[((gg<<7) + (wc<<5) + (ni2<<4) + l15)*72 + (ks<<5) + (l4<<3)];
        #pragma unroll
        for (int gg=0;gg<3;++gg)
          #pragma unroll
          for (int mi2=0;mi2<4;++mi2)
            #pragma unroll
            for (int ni2=0;ni2<2;++ni2)
              acc[gg][mi2][ni2] = __builtin_amdgcn_mfma_f32_16x16x32_bf16(af[mi2], bf[gg][ni2], acc[gg][mi2][ni2], 0,0,0);
      }
    }
    // epilogue: gates + logit partials
    const int bb = by>>1;
    const float* sp = sproj_t + (size_t)bb*TH_;
    const int jbase = (bx<<7) + (wc<<5);
    float spv[3][2], wcv[3][2], bhnv[2], dwv[2];
    #pragma unroll
    for (int ni2=0;ni2<2;++ni2){
      const int j = jbase + (ni2<<4) + l15;
      spv[0][ni2] = sp[j]; spv[1][ni2] = sp[512+j]; spv[2][ni2] = sp[1024+j];
      wcv[0][ni2] = wchk[j]; wcv[1][ni2] = wchk[512+j]; wcv[2][ni2] = wchk[1024+j];
      bhnv[ni2] = dbhh[1024+j];
      dwv[ni2] = decW[j];
    }
    const float* ckrow = checked + ((size_t)(bb*33 + t))*Y_;
    float lrow[4][4];
    #pragma unroll
    for (int mi2=0;mi2<4;++mi2)
      #pragma unroll
      for (int q=0;q<4;++q) lrow[mi2][q] = 0.f;
    #pragma unroll
    for (int mi2=0;mi2<4;++mi2){
      #pragma unroll
      for (int q=0;q<4;++q){
        const int row = bm + wm + (mi2<<4) + (l4<<2) + q;
        const float ck = ckrow[row & 255];
        #pragma unroll
        for (int ni2=0;ni2<2;++ni2){
          const int j = jbase + (ni2<<4) + l15;
          const float g0 = b2f(gib[(size_t)row*TH_ + j]);
          const float g1 = b2f(gib[(size_t)row*TH_ + 512 + j]);
          const float g2 = b2f(gib[(size_t)row*TH_ + 1024 + j]);
          const float hold = b2f(A[(size_t)row*H_ + j]);
          const float r  = sigf(g0 + spv[0][ni2] + ck*wcv[0][ni2] + acc[0][mi2][ni2][q]);
          const float zg = sigf(g1 + spv[1][ni2] + ck*wcv[1][ni2] + acc[1][mi2][ni2][q]);
          const float n  = tanh_fast(g2 + spv[2][ni2] + ck*wcv[2][ni2] + r*(acc[2][mi2][ni2][q] + bhnv[ni2]));
          const float h2 = (1.f - zg)*n + zg*hold;
          h2bo[(size_t)row*H_ + j] = f2b(h2);
          lrow[mi2][q] += h2 * dwv[ni2];
        }
      }
    }
    #pragma unroll
    for (int mi2=0;mi2<4;++mi2)
      #pragma unroll
      for (int q=0;q<4;++q){
        float v = lrow[mi2][q];
        v += __shfl_xor(v,1); v += __shfl_xor(v,2); v += __shfl_xor(v,4); v += __shfl_xor(v,8);
        if (l15==0){
          const int row = bm + wm + (mi2<<4) + (l4<<2) + q;
          atomicAdd(&LW[row], v);
        }
      }
  } else {
    // ---------------- loss role (step t-1) ----------------
    if (t == 0) return;
    const int km1 = t - 1;
    const int lb = blockIdx.x - 256;   // 0..16
    float* red = (float*)smem;
    if (lb < 16){
      // chk loss, 512 rows per block
      const int row = lb*512 + tid;
      const int bb = row>>8, yy = row&255;
      const float u = chkdotR[row] + cb2v[0];
      chkdotR[row] = 0.f;   // reset for reuse at step t+1's chk
      const float c = checked[((size_t)bb*33 + km1 + 1)*Y_ + yy];
      const float yt = yv[((size_t)bb*SOUT_ + km1)*Y_ + yy];
      red[tid] = yt * (c*splus(-u) + (1.f-c)*splus(u));
      __syncthreads();
      for (int o=256;o;o>>=1){ if (tid<o) red[tid] += red[tid+o]; __syncthreads(); }
      if (tid==0) atomicAdd(accv+1, red[0]);
    } else {
      // logit softmax loss over LR (complete since previous launch)
      const int bb = tid>>4, part = tid&15;
      const float* lg = LR + bb*Y_ + part*16;
      float lv[16];
      float m = -1e30f;
      #pragma unroll
      for (int i=0;i<16;++i){ lv[i] = lg[i]; m = fmaxf(m, lv[i]); }
      m = fmaxf(m, __shfl_xor(m,1)); m = fmaxf(m, __shfl_xor(m,2));
      m = fmaxf(m, __shfl_xor(m,4)); m = fmaxf(m, __shfl_xor(m,8));
      float se = 0.f;
      #pragma unroll
      for (int i=0;i<16;++i) se += __expf(lv[i]-m);
      se += __shfl_xor(se,1); se += __shfl_xor(se,2); se += __shfl_xor(se,4); se += __shfl_xor(se,8);
      const float lse = m + logf(se);
      const float* yr = yv + ((size_t)bb*SOUT_ + km1)*Y_ + part*16;
      float pl = 0.f;
      #pragma unroll
      for (int i=0;i<16;++i) pl += yr[i]*(lv[i]-lse);
      pl += __shfl_xor(pl,1); pl += __shfl_xor(pl,2); pl += __shfl_xor(pl,4); pl += __shfl_xor(pl,8);
      red[tid] = (part==0) ? pl : 0.f;
      __syncthreads();
      for (int o=256;o;o>>=1){ if (tid<o) red[tid] += red[tid+o]; __syncthreads(); }
      if (tid==0) atomicAdd(accv+0, -red[0]);
      __syncthreads();
      for (int i=tid; i<8192; i+=512) LR[i] = 0.f;   // ready for step t+1's dec
    }
  }
}

__global__ void k_final(const float* __restrict__ acc, float* __restrict__ out)
{
  if (threadIdx.x==0){
    const float ls = acc[0], cls = acc[1], ys = acc[2];
    out[0] = (ls+cls)/ys; out[1] = ls/ys; out[2] = cls/ys;
  }
}

// ---------------- host ----------------
extern "C" void kernel_launch(void* const* d_in, const int* in_sizes, int n_in,
                              void* d_out, int out_size, void* d_ws, size_t ws_size,
                              hipStream_t stream)
{
  (void)in_sizes; (void)n_in; (void)out_size;
  const int*   x      = (const int*)d_in[0];
  const int*   akey   = (const int*)d_in[1];
  const int*   atype  = (const int*)d_in[2];
  const int*   croom  = (const int*)d_in[3];
  const float* checked= (const float*)d_in[4];
  const float* yv     = (const float*)d_in[5];
  const float* emb    = (const float*)d_in[6];
  const float* attab  = (const float*)d_in[7];
  const float* eWihF  = (const float*)d_in[8];
  const float* eWhhF  = (const float*)d_in[9];
  const float* ebihF  = (const float*)d_in[10];
  const float* ebhhF  = (const float*)d_in[11];
  const float* eWihB  = (const float*)d_in[12];
  const float* eWhhB  = (const float*)d_in[13];
  const float* ebihB  = (const float*)d_in[14];
  const float* ebhhB  = (const float*)d_in[15];
  const float* transW = (const float*)d_in[16];
  const float* transb = (const float*)d_in[17];
  const float* mergeW = (const float*)d_in[18];
  const float* mergeb = (const float*)d_in[19];
  const float* dWih   = (const float*)d_in[20];
  const float* dWhh   = (const float*)d_in[21];
  const float* dbih   = (const float*)d_in[22];
  const float* dbhh   = (const float*)d_in[23];
  const float* dW     = (const float*)d_in[24];
  const float* cW1    = (const float*)d_in[26];
  const float* cb1    = (const float*)d_in[27];
  const float* cW2    = (const float*)d_in[28];
  const float* cb2    = (const float*)d_in[29];

  char* base = (char*)d_ws;
  size_t off = 0;
  auto alloc = [&](size_t bytes)->char*{ char* p = base + off; off += (bytes + 255) & ~(size_t)255; return p; };

  float*  accv   = (float*)alloc(256);
  ushort* embxs  = (ushort*)alloc((size_t)SIN_*B_*E_*2);
  ushort* aemb   = (ushort*)alloc((size_t)Y_*E_*2);
  ushort* aembT  = (ushort*)alloc((size_t)Y_*E_*2);
  float*  avec   = (float*)alloc((size_t)Y_*32*4);
  ushort* yprev  = (ushort*)alloc((size_t)SOUT_*B_*Y_*2);
  ushort* acat   = (ushort*)alloc((size_t)SOUT_*B_*512*2);
  ushort* gi_fb  = (ushort*)alloc((size_t)2*SIN_*B_*TH_*2);
  ushort* gi_f   = gi_fb;
  ushort* gi_b   = gi_fb + (size_t)SIN_*B_*TH_;
  ushort* gibase = gi_fb;
  ushort* encout = (ushort*)alloc((size_t)B_*SIN_*1024*2);
  ushort* encoutT= (ushort*)alloc((size_t)B_*1024*SIN_*2);
  float*  hTf    = (float*)alloc((size_t)B_*H_*4);
  float*  hTb    = (float*)alloc((size_t)B_*H_*4);
  float*  h0dec  = (float*)alloc((size_t)B_*H_*4);
  ushort* esum   = (ushort*)alloc((size_t)B_*SIN_*E_*2);
  float*  scores = (float*)alloc((size_t)B_*Y_*SIN_*4);
  ushort* alpha  = (ushort*)alloc((size_t)B_*Y_*SIN_*2);
  ushort* att    = (ushort*)alloc((size_t)8192*1024*2);
  ushort* chkbase= (ushort*)alloc((size_t)8192*H_*2);
  float*  addy   = (float*)alloc((size_t)Y_*TH_*4);
  float*  addcy  = (float*)alloc((size_t)Y_*H_*4);
  float*  sproj  = (float*)alloc((size_t)SOUT_*B_*TH_*4);
  float*  wchk   = (float*)alloc((size_t)TH_*4);
  float*  dbhhrz = (float*)alloc((size_t)TH_*4);
  ushort* WihFb  = (ushort*)alloc((size_t)TH_*E_*2);
  ushort* WihBb  = (ushort*)alloc((size_t)TH_*E_*2);
  ushort* Wtrb   = (ushort*)alloc((size_t)E_*1024*2);
  ushort* Wattb  = (ushort*)alloc((size_t)TH_*1024*2);
  ushort* Wcat2b = (ushort*)alloc((size_t)TH_*512*2);
  ushort* W1attb = (ushort*)alloc((size_t)H_*1024*2);
  ushort* Wdecb  = (ushort*)alloc((size_t)TH_*512*2);
  ushort* Wchk2b = (ushort*)alloc((size_t)512*512*2);
  ushort* h2bA   = (ushort*)alloc((size_t)8192*H_*2);
  ushort* h2bB   = (ushort*)alloc((size_t)8192*H_*2);
  float*  C0     = (float*)alloc((size_t)8192*4);
  float*  C1     = (float*)alloc((size_t)8192*4);
  float*  L0     = (float*)alloc((size_t)8192*4);
  float*  L1     = (float*)alloc((size_t)8192*4);
  ushort* hG     = (ushort*)alloc((size_t)2*2*32*512*2);
  uint*   flags  = (uint*)alloc((size_t)256*4);

  if (off > ws_size){ k_wsfail<<<1,1,0,stream>>>((float*)d_out); return; }

  float* outp = (float*)d_out;

  k_init<<<dim3(1), dim3(64), 0, stream>>>(accv);
  k_init_enc<<<dim3(64), dim3(256), 0, stream>>>(flags, hG);
  k_ysum<<<dim3(256), dim3(256), 0, stream>>>(yv, accv);
  k_lookup<<<dim3(2048), dim3(256), 0, stream>>>(x, akey, atype, croom, yv, emb, attab,
                                                 embxs, aemb, aembT, avec, acat, yprev);
  k_convall<<<dim3(2048), dim3(256), 0, stream>>>(eWihF, eWihB, transW, dWih, cW1, dWhh,
                                                  WihFb, WihBb, Wtrb, Wattb, Wcat2b, W1attb, Wdecb, Wchk2b);
  k_prep2<<<dim3(1024), dim3(256), 0, stream>>>(avec, dWih, dbih, cW1, cb1, dbhh,
                                                addy, addcy, wchk, dbhhrz);

  // encoder input projections (bias folded in)
  gemm_nt<(GF_BIAS|GF_WBF16)><<<dim3(12,32,1), dim3(256), 0, stream>>>(
    embxs, WihFb, ebihF, nullptr, 0, nullptr, gi_f, TH_, E_, E_, E_, 0, 0L,0L,0L, nullptr);
  gemm_nt<(GF_BIAS|GF_WBF16)><<<dim3(12,32,1), dim3(256), 0, stream>>>(
    embxs, WihBb, ebihB, nullptr, 0, nullptr, gi_b, TH_, E_, E_, E_, 0, 0L,0L,0L, nullptr);

  enc_persist<<<dim3(64), dim3(256), 0, stream>>>(eWhhF, eWhhB, ebhhF, ebhhB, gi_f, gi_b,
                                                  hG, flags, encout, encoutT, hTf, hTb);

  // esum = bf16( tanh(enc_out @ trans_W^T + b) + emb )
  gemm_nt<(GF_BIAS|GF_TANH|GF_ESUM|GF_WBF16)><<<dim3(2,32,1), dim3(256), 0, stream>>>(
    encout, Wtrb, transb, nullptr, 0, nullptr, esum, E_, 1024, 1024, 1024, 0, 0L,0L,0L, embxs);

  // scores[b] = action_emb @ embsum_b^T
  gemm_nt<GF_WF32><<<dim3(1,2,32), dim3(256), 0, stream>>>(
    aemb, esum, nullptr, nullptr, 0, scores, nullptr, SIN_, E_, E_, E_, 0,
    0L, (long)SIN_*E_, (long)Y_*SIN_, nullptr);
  k_softmax<<<dim3(2048), dim3(256), 0, stream>>>(scores, alpha);

  // attention[b] = alpha_b @ enc_out_b
  gemm_nt<GF_WBF16><<<dim3(8,2,32), dim3(256), 0, stream>>>(
    alpha, encoutT, nullptr, nullptr, 0, nullptr, att, 1024, SIN_, SIN_, SIN_, 0,
    (long)Y_*SIN_, (long)1024*SIN_, (long)Y_*1024, nullptr);

  k_merge<<<dim3(32), dim3(512), 0, stream>>>(hTf, hTb, mergeW, mergeb, h0dec);

  // yemb -> acat[:,256:512]
  gemm_nt<GF_WBF16><<<dim3(2,8,1), dim3(256), 0, stream>>>(
    yprev, aembT, nullptr, nullptr, 0, nullptr, acat+256, 512, Y_, Y_, Y_, 0, 0L,0L,0L, nullptr);
  // sproj = acat @ Wcat2^T + dbhh_rz
  gemm_nt<(GF_BIAS|GF_WF32)><<<dim3(12,8,1), dim3(256), 0, stream>>>(
    acat, Wcat2b, dbhhrz, nullptr, 0, sproj, nullptr, TH_, 512, 512, 512, 0, 0L,0L,0L, nullptr);

  // gi_base = att @ W_att^T + add_y[y]   ;  chk_base = att @ W1_att^T + addc_y[y]
  gemm_nt<(GF_WBF16|GF_ADDY)><<<dim3(12,64,1), dim3(256), 0, stream>>>(
    att, Wattb, nullptr, addy, TH_, nullptr, gibase, TH_, 1024, 1024, 1024, 0, 0L,0L,0L, nullptr);
  gemm_nt<(GF_WBF16|GF_ADDY)><<<dim3(4,64,1), dim3(256), 0, stream>>>(
    att, W1attb, nullptr, addcy, H_, nullptr, chkbase, H_, 1024, 1024, 1024, 0, 0L,0L,0L, nullptr);

  k_bcast<<<dim3(1024), dim3(256), 0, stream>>>(h0dec, h2bA, L0, L1, C0, C1);

  // decoder: per k, one launch {dec(k) + losses(k-1)} + one lean chk(k) GEMM.
  for (int k=0; k<=SOUT_; ++k){
    const ushort* hin = (k&1) ? h2bB : h2bA;     // H(k)
    ushort* hout      = (k&1) ? h2bA : h2bB;     // H(k+1)
    float* LWp = (k&1) ? L1 : L0;                // logits of step k (zeroed)
    float* LRp = (k&1) ? L0 : L1;                // logits of step k-1 (complete)
    float* Cw  = (k&1) ? C1 : C0;                // chkdot of step k (zeroed)
    float* Cr  = (k&1) ? C0 : C1;                // chkdot of step k-1 (complete)
    const int ks = (k < SOUT_) ? k : 0;
    gemm_dec2<<<dim3(273), dim3(512), 0, stream>>>(
      hin, Wdecb, gibase, sproj + (size_t)ks*B_*TH_, wchk, dbhh, checked, k,
      dW, hout, LWp, Cr, cb2, yv, LRp, accv);
    if (k < SOUT_){
      gemm_nt<GF_CHK><<<dim3(4,64), dim3(256), 0, stream>>>(
        hout, Wchk2b, nullptr, cW2, 0, Cw, nullptr, 0, 512, 512, 512, 0,
        0L,0L,0L, chkbase);
    }
  }
  k_final<<<dim3(1), dim3(1), 0, stream>>>(accv, outp);
}

// Round 8
// 3880.880 us; speedup vs baseline: 1.7158x; 1.0139x over previous
//
#include <hip/hip_runtime.h>

typedef unsigned short ushort;
typedef unsigned int uint;
typedef __attribute__((ext_vector_type(8))) short short8;
typedef __attribute__((ext_vector_type(4))) float f32x4;
typedef __attribute__((ext_vector_type(4))) uint u32x4;

#define DEVI __device__ __forceinline__

#define B_ 32
#define SIN_ 128
#define SOUT_ 32
#define Y_ 256
#define H_ 512
#define E_ 256
#define TH_ 1536

DEVI float b2f(ushort u){ return __uint_as_float(((uint)u)<<16); }
DEVI ushort f2b(float f){ uint x = __float_as_uint(f); return (ushort)((x + 0x7FFFu + ((x>>16)&1u)) >> 16); }
DEVI float sigf(float x){ return 1.f/(1.f+__expf(-x)); }
DEVI float tanh_fast(float x){ return 2.f/(1.f+__expf(-2.f*x)) - 1.f; }
DEVI float splus(float x){ return fmaxf(x,0.f) + log1pf(__expf(-fabsf(x))); }
DEVI short8 cvt8(u32x4 v){ return __builtin_bit_cast(short8, v); }

// sc0 sc1 = coherent through Infinity Cache (cross-XCD visible without fences)
DEVI uint ld_flag(const uint* p){
  uint r;
  asm volatile("global_load_dword %0, %1, off sc0 sc1\n\ts_waitcnt vmcnt(0)"
               : "=v"(r) : "v"(p) : "memory");
  return r;
}
DEVI void st_flag(uint* p, uint v){
  asm volatile("global_store_dword %0, %1, off sc0 sc1" :: "v"(p), "v"(v) : "memory");
}
DEVI void st_h16(ushort* p, uint v){
  asm volatile("global_store_short %0, %1, off sc0 sc1" :: "v"(p), "v"(v) : "memory");
}
DEVI void stf_sc1(float* p, float v){
  asm volatile("global_store_dword %0, %1, off sc0 sc1" :: "v"(p), "v"(__float_as_uint(v)) : "memory");
}
DEVI f32x4 ld4f_sc1(const float* p){
  u32x4 r;
  asm volatile("global_load_dwordx4 %0, %1, off sc0 sc1\n\ts_waitcnt vmcnt(0)"
               : "=v"(r) : "v"(p) : "memory");
  return __builtin_bit_cast(f32x4, r);
}
// 16 contiguous floats, coherent
DEVI void ld16_sc1(const float* p, float* o){
  u32x4 r0,r1,r2,r3;
  asm volatile("global_load_dwordx4 %0, %4, off sc0 sc1\n\t"
               "global_load_dwordx4 %1, %4, off offset:16 sc0 sc1\n\t"
               "global_load_dwordx4 %2, %4, off offset:32 sc0 sc1\n\t"
               "global_load_dwordx4 %3, %4, off offset:48 sc0 sc1\n\t"
               "s_waitcnt vmcnt(0)"
               : "=&v"(r0),"=&v"(r1),"=&v"(r2),"=&v"(r3) : "v"(p) : "memory");
  *(u32x4*)(o) = r0; *(u32x4*)(o+4) = r1; *(u32x4*)(o+8) = r2; *(u32x4*)(o+12) = r3;
}
// two 16B coherent loads (blocking)
DEVI void lda2_sc1(const ushort* p0, const ushort* p1, u32x4& r0, u32x4& r1){
  asm volatile("global_load_dwordx4 %0, %2, off sc0 sc1\n\t"
               "global_load_dwordx4 %1, %3, off sc0 sc1\n\t"
               "s_waitcnt vmcnt(0)"
               : "=&v"(r0), "=&v"(r1) : "v"(p0), "v"(p1) : "memory");
}

// ---------------- init / reductions ----------------
__global__ void k_init(float* acc){ if (threadIdx.x < 4) acc[threadIdx.x] = 0.f; }

__global__ void k_wsfail(float* out){ out[0]=1.2345e8f; out[1]=2.3456e8f; out[2]=3.4567e8f; }

__global__ void k_init_enc(uint* __restrict__ flags, ushort* __restrict__ hG)
{
  const int id = blockIdx.x*256 + threadIdx.x;
  if (id < 256) flags[id] = 0u;
  if (id < 8192) ((uint4*)hG)[id] = make_uint4(0,0,0,0);
}

__global__ __launch_bounds__(256) void k_ysum(const float* __restrict__ yv, float* __restrict__ acc)
{
  __shared__ float red[256];
  float s = 0.f;
  for (long i = (long)blockIdx.x*256 + threadIdx.x; i < (long)B_*SOUT_*Y_; i += (long)gridDim.x*256) s += yv[i];
  red[threadIdx.x] = s; __syncthreads();
  for (int o=128;o;o>>=1){ if ((int)threadIdx.x<o) red[threadIdx.x] += red[threadIdx.x+o]; __syncthreads(); }
  if (threadIdx.x==0) atomicAdd(acc+2, red[0]);
}

// ---------------- embedding / lookup ----------------
__global__ void k_lookup(const int* __restrict__ x, const int* __restrict__ akey,
                         const int* __restrict__ atype, const int* __restrict__ croom,
                         const float* __restrict__ yv,
                         const float* __restrict__ emb, const float* __restrict__ attab,
                         ushort* __restrict__ embxs, ushort* __restrict__ aemb,
                         ushort* __restrict__ aembT, float* __restrict__ avec,
                         ushort* __restrict__ acat, ushort* __restrict__ yprev)
{
  const long N1 = (long)SIN_*B_*E_;
  const long N2 = (long)Y_*E_;
  const long N3 = (long)Y_*32;
  const long N4 = (long)SOUT_*B_*E_;
  const long N5 = (long)SOUT_*B_*Y_;
  for (long i = (long)blockIdx.x*blockDim.x + threadIdx.x; i < N1+N2+N3+N4+N5; i += (long)gridDim.x*blockDim.x){
    long id = i;
    if (id < N1){
      int e = id & 255; long sb = id >> 8; int bb = (int)(sb & 31); int s = (int)(sb >> 5);
      embxs[id] = f2b(emb[(size_t)x[bb*SIN_ + s]*E_ + e]);
    } else if ((id -= N1) < N2){
      int e = (int)(id & 255), yy = (int)(id >> 8);
      ushort v = f2b(emb[(size_t)akey[yy]*E_ + e]);
      aemb[yy*E_ + e] = v;
      aembT[e*Y_ + yy] = v;
    } else if ((id -= N2) < N3){
      int a = (int)(id & 31), yy = (int)(id >> 5);
      avec[yy*32 + a] = attab[atype[yy]*32 + a];
    } else if ((id -= N3) < N4){
      int e = (int)(id & 255); long tb = id >> 8; int bb = (int)(tb & 31); int t = (int)(tb >> 5);
      acat[(size_t)tb*512 + e] = f2b(emb[(size_t)croom[bb*SOUT_ + t]*E_ + e]);
    } else { id -= N4;
      int yy = (int)(id & 255); long tb = id >> 8; int bb = (int)(tb & 31); int t = (int)(tb >> 5);
      yprev[id] = (t == 0) ? (ushort)0 : f2b(yv[((size_t)bb*SOUT_ + (t-1))*Y_ + yy]);
    }
  }
}

// all f32->bf16 weight conversions in one kernel
__global__ __launch_bounds__(256)
void k_convall(const float* __restrict__ eWihF, const float* __restrict__ eWihB,
               const float* __restrict__ transW, const float* __restrict__ dWih,
               const float* __restrict__ cW1, const float* __restrict__ dWhh,
               ushort* __restrict__ WihFb, ushort* __restrict__ WihBb,
               ushort* __restrict__ Wtrb, ushort* __restrict__ Wattb,
               ushort* __restrict__ Wcat2b, ushort* __restrict__ W1attb,
               ushort* __restrict__ Wdecb, ushort* __restrict__ Wchk2b)
{
  const long N1 = 393216;
  const long N2 = 393216;
  const long N3 = 262144;
  const long N4 = 1572864;
  const long N5 = 393216;
  const long N6 = 393216;
  const long N7 = 524288;
  const long N8 = 786432;
  const long N9 = 262144;
  const long NT = N1+N2+N3+N4+N5+N6+N7+N8+N9;
  for (long i = (long)blockIdx.x*256 + threadIdx.x; i < NT; i += (long)gridDim.x*256){
    long id = i;
    if (id < N1){ WihFb[id] = f2b(eWihF[id]); }
    else if ((id -= N1) < N2){ WihBb[id] = f2b(eWihB[id]); }
    else if ((id -= N2) < N3){ Wtrb[id] = f2b(transW[id]); }
    else if ((id -= N3) < N4){
      const long r = id>>10, c = id&1023;
      Wattb[id] = f2b(dWih[r*1569 + c]);
    }
    else if ((id -= N4) < N5){
      const long r = id>>8, c = id&255;
      Wcat2b[r*512 + c] = f2b(dWih[r*1569 + 1025 + c]);
    }
    else if ((id -= N5) < N6){
      const long r = id>>8, c = id&255;
      Wcat2b[r*512 + 256 + c] = f2b(dWih[r*1569 + 1313 + c]);
    }
    else if ((id -= N6) < N7){
      const long r = id>>10, c = id&1023;
      W1attb[id] = f2b(cW1[r*1568 + c]);
    }
    else if ((id -= N7) < N8){ Wdecb[id] = f2b(dWhh[id]); }
    else { id -= N8;
      const long r = id>>9, c = id&511;
      Wchk2b[id] = f2b(cW1[r*1568 + 1056 + c]);
    }
  }
}

// add_y, addc_y, wchk, dbhh_rz
__global__ void k_prep2(const float* __restrict__ avec, const float* __restrict__ decWih,
                        const float* __restrict__ dbih, const float* __restrict__ cW1,
                        const float* __restrict__ cb1, const float* __restrict__ dbhh,
                        float* __restrict__ addy, float* __restrict__ addcy,
                        float* __restrict__ wchk, float* __restrict__ dbhhrz)
{
  const long NA = (long)Y_*TH_;
  const long NB = (long)Y_*H_;
  for (long i = (long)blockIdx.x*blockDim.x + threadIdx.x; i < NA+NB+TH_+TH_; i += (long)gridDim.x*blockDim.x){
    long id = i;
    if (id < NA){
      int n = (int)(id % TH_), yy = (int)(id / TH_);
      float s = dbih[n];
      const float* wr = decWih + (size_t)n*1569 + 1281;
      const float* av = avec + yy*32;
      #pragma unroll
      for (int a=0;a<32;++a) s += av[a]*wr[a];
      addy[id] = s;
    } else if ((id -= NA) < NB){
      int n = (int)(id & 511), yy = (int)(id >> 9);
      float s = cb1[n];
      const float* wr = cW1 + (size_t)n*1568 + 1024;
      const float* av = avec + yy*32;
      #pragma unroll
      for (int a=0;a<32;++a) s += av[a]*wr[a];
      addcy[id] = s;
    } else if ((id -= NB) < TH_){
      wchk[id] = decWih[(size_t)id*1569 + 1024];
    } else { id -= TH_;
      dbhhrz[id] = (id < 1024) ? dbhh[id] : 0.f;
    }
  }
}

// ---------------- bf16 NT GEMM: C[M,N] = A[M,K] @ W[N,K]^T  (MFMA 16x16x32) ----------------
#define GF_BIAS 1
#define GF_TANH 2
#define GF_WF32 4
#define GF_WBF16 8
#define GF_ADDY 32
#define GF_ESUM 128

template<int FLAGS>
__global__ __launch_bounds__(256)
void gemm_nt(const ushort* __restrict__ A, const ushort* __restrict__ W,
             const float* __restrict__ bias,
             const float* __restrict__ addy, int lday,
             float* __restrict__ Cf, ushort* __restrict__ Cb, int ldC,
             int K, int ldA, int ldW, int n0,
             long zA, long zW, long zC,
             const ushort* __restrict__ chkbase)
{
  const int z = blockIdx.z;
  A += (long)z*zA; W += (long)z*zW;
  const int bn = n0 + (blockIdx.x<<7);
  const int bm = (blockIdx.y<<7);
  const int tid = threadIdx.x;
  const int w = tid>>6, lane = tid&63;
  const int wm = (w>>1)<<6, wn = (w&1)<<6;
  const int rs = tid>>1;
  const int kh = (tid&1)<<5;
  __shared__ ushort lsA[8192];
  __shared__ ushort lsB[8192];
  f32x4 acc[4][4];
  #pragma unroll
  for (int i=0;i<4;++i)
    #pragma unroll
    for (int jj=0;jj<4;++jj) acc[i][jj] = 0.f;

  const ushort* pa = A + (size_t)(bm+rs)*ldA + kh;
  const ushort* pb = W + (size_t)(bn+rs)*ldW + kh;
  uint4 va[4], vb[4];
  #pragma unroll
  for (int i=0;i<4;++i){ va[i] = *(const uint4*)(pa + i*8); vb[i] = *(const uint4*)(pb + i*8); }
  const int nkt = K>>6;
  for (int kt=0; kt<nkt; ++kt){
    __syncthreads();
    #pragma unroll
    for (int i=0;i<4;++i){
      const int c = ((tid&1)<<2) + i;
      *(uint4*)&lsA[(size_t)((c<<7) + rs)<<3] = va[i];
      *(uint4*)&lsB[(size_t)((c<<7) + rs)<<3] = vb[i];
    }
    __syncthreads();
    if (kt+1 < nkt){
      const ushort* qa = pa + (size_t)(kt+1)*64;
      const ushort* qb = pb + (size_t)(kt+1)*64;
      #pragma unroll
      for (int i=0;i<4;++i){ va[i] = *(const uint4*)(qa + i*8); vb[i] = *(const uint4*)(qb + i*8); }
    }
    #pragma unroll
    for (int ks=0;ks<2;++ks){
      const int ch = (ks<<2) + (lane>>4);
      short8 af[4], bf[4];
      #pragma unroll
      for (int mi=0;mi<4;++mi) af[mi] = *(const short8*)&lsA[(size_t)((ch<<7) + wm + (mi<<4) + (lane&15))<<3];
      #pragma unroll
      for (int ni=0;ni<4;++ni) bf[ni] = *(const short8*)&lsB[(size_t)((ch<<7) + wn + (ni<<4) + (lane&15))<<3];
      #pragma unroll
      for (int mi=0;mi<4;++mi)
        #pragma unroll
        for (int ni=0;ni<4;++ni)
          acc[mi][ni] = __builtin_amdgcn_mfma_f32_16x16x32_bf16(af[mi], bf[ni], acc[mi][ni], 0,0,0);
    }
  }
  const long zc = (long)z*zC;
  #pragma unroll
  for (int mi=0;mi<4;++mi){
    #pragma unroll
    for (int ni=0;ni<4;++ni){
      const int col = bn + wn + (ni<<4) + (lane&15);
      const int row0 = bm + wm + (mi<<4) + ((lane>>4)<<2);
      float bv = 0.f;
      if (FLAGS & GF_BIAS) bv = bias[col];
      #pragma unroll
      for (int q=0;q<4;++q){
        const int row = row0 + q;
        float xv = acc[mi][ni][q] + bv;
        if (FLAGS & GF_ADDY) xv += addy[(size_t)(row&255)*lday + col];
        if (FLAGS & GF_TANH) xv = tanh_fast(xv);
        if (FLAGS & GF_ESUM) xv += b2f(chkbase[((size_t)(row&127)*32 + (row>>7))*256 + col]);
        if (FLAGS & GF_WF32)  Cf[zc + (size_t)row*ldC + col] = xv;
        if (FLAGS & GF_WBF16) Cb[zc + (size_t)row*ldC + col] = f2b(xv);
      }
    }
  }
}

// ---------------- persistent bi-GRU encoder (fence-free sc1 exchange, hi-only bf16 h) ----------------
__global__ __launch_bounds__(256,1)
void enc_persist(const float* __restrict__ Wf, const float* __restrict__ Wb,
                 const float* __restrict__ bhf, const float* __restrict__ bhb,
                 const ushort* __restrict__ gif, const ushort* __restrict__ gib,
                 ushort* __restrict__ hG, uint* __restrict__ flags,
                 ushort* __restrict__ encout, ushort* __restrict__ encoutT,
                 float* __restrict__ hTf, float* __restrict__ hTb)
{
  const int g = blockIdx.x;
  const int dir = g >> 5;
  const int j0 = (g & 31) << 4;
  const int tid = threadIdx.x;
  const int w = tid >> 6, lane = tid & 63;
  const int mi = w & 1, kh = w >> 1;
  const int l15 = lane & 15, l4 = lane >> 4;
  const int brow0 = mi*16 + l4*4;

  const float* W = dir ? Wb : Wf;
  const float* bh = dir ? bhb : bhf;
  const ushort* gi = dir ? gib : gif;

  __shared__ __align__(16) float cred[2][3][256];
  __shared__ float bhl[48];

  short8 bw[3][8];
  {
    const int kbase = kh*256 + l4*8;
    #pragma unroll
    for (int ni=0; ni<3; ++ni){
      const float* wr = W + (size_t)(ni*512 + j0 + l15)*512 + kbase;
      #pragma unroll
      for (int ks=0; ks<8; ++ks){
        const float4 f0 = *(const float4*)(wr + ks*32);
        const float4 f1 = *(const float4*)(wr + ks*32 + 4);
        short8 v;
        v[0]=(short)f2b(f0.x); v[1]=(short)f2b(f0.y); v[2]=(short)f2b(f0.z); v[3]=(short)f2b(f0.w);
        v[4]=(short)f2b(f1.x); v[5]=(short)f2b(f1.y); v[6]=(short)f2b(f1.z); v[7]=(short)f2b(f1.w);
        bw[ni][ks] = v;
      }
    }
  }
  if (tid < 48) bhl[tid] = bh[(tid>>4)*512 + j0 + (tid&15)];
  __syncthreads();

  float bh0r=0.f, bh1r=0.f, bh2r=0.f;
  if (kh==0){ bh0r = bhl[l15]; bh1r = bhl[16+l15]; bh2r = bhl[32+l15]; }
  float holdr[4] = {0.f,0.f,0.f,0.f};
  uint* myflag = flags + dir*32 + (g&31);

  for (int t=0; t<128; ++t){
    const int tt = dir ? (127 - t) : t;
    float giv0[4], giv1[4], giv2[4];
    if (kh==0){
      const ushort* girow = gi + ((size_t)tt*32 + brow0)*1536 + j0 + l15;
      #pragma unroll
      for (int q=0; q<4; ++q){
        giv0[q] = b2f(girow[q*1536]);
        giv1[q] = b2f(girow[q*1536 + 512]);
        giv2[q] = b2f(girow[q*1536 + 1024]);
      }
    }
    if (t){
      if ((tid>>6)==2 && (tid&63)<32){
        const uint* fp = flags + dir*32 + (tid&31);
        while (ld_flag(fp) < (uint)t) __builtin_amdgcn_s_sleep(2);
      }
      __syncthreads();
    }
    const ushort* hsrc = hG + ((size_t)((t&1)*2 + dir))*16384 + (size_t)(mi*16+l15)*512 + kh*256 + l4*8;
    u32x4 a0,a1,a2,a3,a4,a5,a6,a7;
    asm volatile(
      "global_load_dwordx4 %0, %8, off sc0 sc1\n\t"
      "global_load_dwordx4 %1, %8, off offset:64 sc0 sc1\n\t"
      "global_load_dwordx4 %2, %8, off offset:128 sc0 sc1\n\t"
      "global_load_dwordx4 %3, %8, off offset:192 sc0 sc1\n\t"
      "global_load_dwordx4 %4, %8, off offset:256 sc0 sc1\n\t"
      "global_load_dwordx4 %5, %8, off offset:320 sc0 sc1\n\t"
      "global_load_dwordx4 %6, %8, off offset:384 sc0 sc1\n\t"
      "global_load_dwordx4 %7, %8, off offset:448 sc0 sc1\n\t"
      "s_waitcnt vmcnt(0)"
      : "=&v"(a0),"=&v"(a1),"=&v"(a2),"=&v"(a3),"=&v"(a4),"=&v"(a5),"=&v"(a6),"=&v"(a7)
      : "v"(hsrc)
      : "memory");
    const short8 ah[8] = {cvt8(a0),cvt8(a1),cvt8(a2),cvt8(a3),cvt8(a4),cvt8(a5),cvt8(a6),cvt8(a7)};
    f32x4 acc[3]; acc[0]=0.f; acc[1]=0.f; acc[2]=0.f;
    #pragma unroll
    for (int ks=0; ks<8; ++ks){
      acc[0] = __builtin_amdgcn_mfma_f32_16x16x32_bf16(ah[ks], bw[0][ks], acc[0],0,0,0);
      acc[1] = __builtin_amdgcn_mfma_f32_16x16x32_bf16(ah[ks], bw[1][ks], acc[1],0,0,0);
      acc[2] = __builtin_amdgcn_mfma_f32_16x16x32_bf16(ah[ks], bw[2][ks], acc[2],0,0,0);
    }
    if (kh==1){
      #pragma unroll
      for (int ni=0; ni<3; ++ni) *(f32x4*)&cred[mi][ni][lane*4] = acc[ni];
    }
    __syncthreads();
    ushort hbs[4];
    if (kh==0){
      #pragma unroll
      for (int ni=0; ni<3; ++ni){
        const f32x4 o = *(const f32x4*)&cred[mi][ni][lane*4];
        acc[ni][0]+=o[0]; acc[ni][1]+=o[1]; acc[ni][2]+=o[2]; acc[ni][3]+=o[3];
      }
      ushort* dst = hG + ((size_t)(((t+1)&1)*2 + dir))*16384;
      #pragma unroll
      for (int q=0; q<4; ++q){
        const int b = brow0 + q;
        const float r  = sigf(giv0[q] + acc[0][q] + bh0r);
        const float zg = sigf(giv1[q] + acc[1][q] + bh1r);
        const float n  = tanh_fast(giv2[q] + r*(acc[2][q] + bh2r));
        const float h2 = (1.f - zg)*n + zg*holdr[q];
        holdr[q] = h2;
        const ushort hb = f2b(h2);
        hbs[q] = hb;
        if (t < 127) st_h16(dst + (size_t)b*512 + j0 + l15, (uint)hb);
      }
    }
    __syncthreads();   // drains kh==0 waves' sc1 h-stores before flag
    if (t < 127 && tid == 0) st_flag(myflag, (uint)(t+1));
    if (kh==0){
      #pragma unroll
      for (int q=0; q<4; ++q){
        const int b = brow0 + q;
        encout[((size_t)b*SIN_ + tt)*1024 + dir*H_ + j0 + l15] = hbs[q];
        encoutT[((size_t)b*1024 + dir*H_ + j0 + l15)*SIN_ + tt] = hbs[q];
      }
    }
  }
  if (kh==0){
    float* hT = dir ? hTb : hTf;
    #pragma unroll
    for (int q=0; q<4; ++q) hT[(size_t)(brow0+q)*H_ + j0 + l15] = holdr[q];
  }
}

// row softmax over SIN=128, one wave per row
__global__ __launch_bounds__(256) void k_softmax(const float* __restrict__ sc, ushort* __restrict__ al)
{
  const int row = blockIdx.x*4 + (threadIdx.x>>6);
  const int lane = threadIdx.x&63;
  const float* s = sc + (size_t)row*SIN_;
  const float2 v = *(const float2*)&s[lane*2];
  float m = fmaxf(v.x, v.y);
  #pragma unroll
  for (int o=1;o<64;o<<=1) m = fmaxf(m, __shfl_xor(m, o));
  const float e0 = __expf(v.x - m), e1 = __expf(v.y - m);
  float sum = e0 + e1;
  #pragma unroll
  for (int o=1;o<64;o<<=1) sum += __shfl_xor(sum, o);
  const float inv = 1.f/sum;
  ushort* a = al + (size_t)row*SIN_;
  const uint pkv = (uint)f2b(e0*inv) | ((uint)f2b(e1*inv)<<16);
  *(uint*)&a[lane*2] = pkv;
}

// h0_dec = tanh(hidden_cat @ merge_W^T + merge_b)
__global__ __launch_bounds__(512)
void k_merge(const float* __restrict__ hTf, const float* __restrict__ hTb,
             const float* __restrict__ mW, const float* __restrict__ mb,
             float* __restrict__ h0)
{
  const int b = blockIdx.x, j = threadIdx.x;
  __shared__ float hc[1024];
  for (int i=j; i<1024; i+=512){
    const int half = i >> 9, jj = i & 511;
    hc[i] = (b < 16) ? hTf[(size_t)(2*b + half)*H_ + jj] : hTb[(size_t)(2*(b-16) + half)*H_ + jj];
  }
  __syncthreads();
  float d = mb[j];
  const float* wr = mW + (size_t)j*1024;
  #pragma unroll 8
  for (int k=0;k<1024;k+=4){
    const float4 a = *(const float4*)&wr[k];
    const float4 hh = *(const float4*)&hc[k];
    d += a.x*hh.x + a.y*hh.y + a.z*hh.z + a.w*hh.w;
  }
  h0[(size_t)b*H_ + j] = tanh_fast(d);
}

__global__ void k_bcast(const float* __restrict__ h0, ushort* __restrict__ hb,
                        uint* __restrict__ flags2)
{
  for (long i = (long)blockIdx.x*blockDim.x + threadIdx.x; i < (long)8192*H_; i += (long)gridDim.x*blockDim.x){
    const int jj = (int)(i & 511); const long row = i >> 9; const int bb = (int)(row >> 8);
    hb[i] = f2b(h0[(size_t)bb*H_ + jj]);
    if (i < 256) flags2[i] = 0u;
  }
}

// ---------------- persistent decoder: all 32 steps in one kernel ----------------
// 256 blocks x 512 threads, 1 block/CU (LDS-forced). Per step:
//   phase D: loss(k-1) [waves 0,1] + dec GEMM+gates (128row x 128col tile) -> h2b sc1, LP partials
//   barrier ; phase C: chk GEMM (128x128) -> CP partials ; barrier
__global__ __launch_bounds__(512,1)
void dec_persist(ushort* __restrict__ hA, ushort* __restrict__ hB,
                 const ushort* __restrict__ Wd, const ushort* __restrict__ gib,
                 const float* __restrict__ sproj, const float* __restrict__ wchk,
                 const float* __restrict__ dbhh, const float* __restrict__ checked,
                 const float* __restrict__ decW,
                 const ushort* __restrict__ Wchk2b, const ushort* __restrict__ chkbase,
                 const float* __restrict__ cw2, const float* __restrict__ cb2v,
                 const float* __restrict__ yv,
                 float* __restrict__ LP0, float* __restrict__ LP1,
                 float* __restrict__ CP, uint* __restrict__ flags,
                 float* __restrict__ accv)
{
  __shared__ __align__(16) ushort lsA_[9216];      // 18 KB (128 x 72)
  __shared__ __align__(16) ushort lsB_[27648];     // 54 KB (384 x 72)
  __shared__ __align__(16) ushort lhold[2][9216];  // 36 KB hold stash
  __shared__ float lred[4][128];                   // 2 KB partial reduce

  const int blk = blockIdx.x;
  const int tid = threadIdx.x;
  const int bx = blk & 3, by = blk >> 2;
  const int bm = by << 7;
  const int w = tid>>6, lane = tid&63;
  const int wrh = w>>2, wc = w&3;
  const int wm = wrh<<6;
  const int l15 = lane&15, l4 = lane>>4;
  const int saRow0 = tid>>3, saK = (tid&7)<<3;
  const float cb2s = cb2v[0];
  int ep = 0;

  for (int k=0; k<=SOUT_; ++k){
    ushort* hin  = (k&1) ? hB : hA;
    ushort* hout = (k&1) ? hA : hB;
    float* LPw = (k&1) ? LP1 : LP0;
    const float* LPr = (k&1) ? LP0 : LP1;

    // ---------- loss(k-1) prefix (waves 0 and 1) ----------
    if (k > 0){
      const int km1 = k-1;
      if (tid < 64){
        float lossv = 0.f;
        if (tid < 32){
          const int row = blk*32 + tid;
          const int bb = row>>8, yy = row&255;
          const f32x4 cp = ld4f_sc1(&CP[(size_t)row*4]);
          const float u = cp[0]+cp[1]+cp[2]+cp[3] + cb2s;
          const float c = checked[((size_t)bb*33 + km1 + 1)*Y_ + yy];
          const float yt = yv[((size_t)bb*SOUT_ + km1)*Y_ + yy];
          lossv = yt * (c*splus(-u) + (1.f-c)*splus(u));
        }
        #pragma unroll
        for (int o=1;o<64;o<<=1) lossv += __shfl_xor(lossv, o);
        if (tid==0) atomicAdd(accv+1, lossv);
      } else if (tid < 128 && blk < 32){
        const int ln = tid - 64;
        float lf[16];
        ld16_sc1(&LPr[(size_t)blk*1024 + ln*16], lf);
        float lv[4];
        #pragma unroll
        for (int r2=0;r2<4;++r2) lv[r2] = lf[r2*4]+lf[r2*4+1]+lf[r2*4+2]+lf[r2*4+3];
        float m = fmaxf(fmaxf(lv[0],lv[1]), fmaxf(lv[2],lv[3]));
        #pragma unroll
        for (int o=1;o<64;o<<=1) m = fmaxf(m, __shfl_xor(m, o));
        float se = 0.f;
        #pragma unroll
        for (int r2=0;r2<4;++r2) se += __expf(lv[r2]-m);
        #pragma unroll
        for (int o=1;o<64;o<<=1) se += __shfl_xor(se, o);
        const float lse = m + logf(se);
        const float* yr = yv + ((size_t)blk*SOUT_ + km1)*Y_ + ln*4;
        float pl = 0.f;
        #pragma unroll
        for (int r2=0;r2<4;++r2) pl += yr[r2]*(lv[r2]-lse);
        #pragma unroll
        for (int o=1;o<64;o<<=1) pl += __shfl_xor(pl, o);
        if (ln==0) atomicAdd(accv+0, -pl);
      }
    }
    if (k == SOUT_) break;

    // ---------- phase D: dec(k) ----------
    {
      const float* sproj_t = sproj + (size_t)k*B_*TH_;
      f32x4 acc[3][4][2];
      #pragma unroll
      for (int gg=0;gg<3;++gg)
        #pragma unroll
        for (int mi2=0;mi2<4;++mi2)
          #pragma unroll
          for (int ni2=0;ni2<2;++ni2) acc[gg][mi2][ni2] = 0.f;

      uint4 vb[6];
      #pragma unroll
      for (int i=0;i<6;++i){
        const int s = tid + (i<<9);
        const int gg = s>>10, w1 = s&1023, row = w1>>3, kc = (w1&7)<<3;
        vb[i] = *(const uint4*)&Wd[(size_t)((gg<<9) + (bx<<7) + row)*512 + kc];
      }
      const ushort* pa0 = hin + (size_t)(bm+saRow0)*512 + saK;
      const ushort* pa1 = pa0 + (size_t)64*512;
      for (int kt=0; kt<8; ++kt){
        u32x4 a0, a1;
        lda2_sc1(pa0 + kt*64, pa1 + kt*64, a0, a1);
        __syncthreads();
        *(u32x4*)&lsA_[saRow0*72 + saK] = a0;
        *(u32x4*)&lsA_[(saRow0+64)*72 + saK] = a1;
        #pragma unroll
        for (int i=0;i<6;++i){
          const int s = tid + (i<<9);
          const int gg = s>>10, w1 = s&1023, row = w1>>3, kc = (w1&7)<<3;
          *(uint4*)&lsB_[((gg<<7)+row)*72 + kc] = vb[i];
        }
        __syncthreads();
        if (kt < 7){
          const int ko = (kt+1)<<6;
          #pragma unroll
          for (int i=0;i<6;++i){
            const int s = tid + (i<<9);
            const int gg = s>>10, w1 = s&1023, row = w1>>3, kc = (w1&7)<<3;
            vb[i] = *(const uint4*)&Wd[(size_t)((gg<<9) + (bx<<7) + row)*512 + ko + kc];
          }
        }
        if ((kt>>1) == bx){
          const int half = kt&1;
          uint4* dst4 = (uint4*)&lhold[half][0];
          const uint4* src4 = (const uint4*)lsA_;
          for (int i=tid; i<1152; i+=512) dst4[i] = src4[i];
        }
        #pragma unroll
        for (int ks=0;ks<2;++ks){
          short8 af[4];
          #pragma unroll
          for (int mi2=0;mi2<4;++mi2)
            af[mi2] = *(const short8*)&lsA_[(wm + (mi2<<4) + l15)*72 + (ks<<5) + (l4<<3)];
          short8 bf[3][2];
          #pragma unroll
          for (int gg=0;gg<3;++gg)
            #pragma unroll
            for (int ni2=0;ni2<2;++ni2)
              bf[gg][ni2] = *(const short8*)&lsB_[((gg<<7) + (wc<<5) + (ni2<<4) + l15)*72 + (ks<<5) + (l4<<3)];
          #pragma unroll
          for (int gg=0;gg<3;++gg)
            #pragma unroll
            for (int mi2=0;mi2<4;++mi2)
              #pragma unroll
              for (int ni2=0;ni2<2;++ni2)
                acc[gg][mi2][ni2] = __builtin_amdgcn_mfma_f32_16x16x32_bf16(af[mi2], bf[gg][ni2], acc[gg][mi2][ni2], 0,0,0);
        }
      }
      __syncthreads();   // lhold complete (cross-thread)
      // epilogue: gates + logit partials
      const int bb = by>>1;
      const float* sp = sproj_t + (size_t)bb*TH_;
      const int jbase = (bx<<7) + (wc<<5);
      float spv[3][2], wcv[3][2], bhnv[2], dwv[2];
      #pragma unroll
      for (int ni2=0;ni2<2;++ni2){
        const int j = jbase + (ni2<<4) + l15;
        spv[0][ni2] = sp[j]; spv[1][ni2] = sp[512+j]; spv[2][ni2] = sp[1024+j];
        wcv[0][ni2] = wchk[j]; wcv[1][ni2] = wchk[512+j]; wcv[2][ni2] = wchk[1024+j];
        bhnv[ni2] = dbhh[1024+j];
        dwv[ni2] = decW[j];
      }
      const float* ckrow = checked + ((size_t)(bb*33 + k))*Y_;
      const int hhalf = wc>>1, hcb = ((wc&1)<<5);
      #pragma unroll
      for (int mi2=0;mi2<4;++mi2){
        float lrow[4];
        #pragma unroll
        for (int q=0;q<4;++q) lrow[q] = 0.f;
        #pragma unroll
        for (int q=0;q<4;++q){
          const int rloc = wm + (mi2<<4) + (l4<<2) + q;
          const int row = bm + rloc;
          const float ck = ckrow[row & 255];
          #pragma unroll
          for (int ni2=0;ni2<2;++ni2){
            const int j = jbase + (ni2<<4) + l15;
            const float g0 = b2f(gib[(size_t)row*TH_ + j]);
            const float g1 = b2f(gib[(size_t)row*TH_ + 512 + j]);
            const float g2 = b2f(gib[(size_t)row*TH_ + 1024 + j]);
            const float hold = b2f(lhold[hhalf][rloc*72 + hcb + (ni2<<4) + l15]);
            const float r  = sigf(g0 + spv[0][ni2] + ck*wcv[0][ni2] + acc[0][mi2][ni2][q]);
            const float zg = sigf(g1 + spv[1][ni2] + ck*wcv[1][ni2] + acc[1][mi2][ni2][q]);
            const float n  = tanh_fast(g2 + spv[2][ni2] + ck*wcv[2][ni2] + r*(acc[2][mi2][ni2][q] + bhnv[ni2]));
            const float h2 = (1.f - zg)*n + zg*hold;
            st_h16(hout + (size_t)row*H_ + j, (uint)f2b(h2));
            lrow[q] += h2 * dwv[ni2];
          }
        }
        #pragma unroll
        for (int q=0;q<4;++q){
          float v = lrow[q];
          v += __shfl_xor(v,1); v += __shfl_xor(v,2); v += __shfl_xor(v,4); v += __shfl_xor(v,8);
          if (l15==0) lred[wc][wm + (mi2<<4) + (l4<<2) + q] = v;
        }
      }
      __syncthreads();
      if (tid < 128){
        const float s = lred[0][tid] + lred[1][tid] + lred[2][tid] + lred[3][tid];
        stf_sc1(&LPw[(size_t)(bm+tid)*4 + bx], s);
      }
    }
    // barrier A
    ++ep;
    __syncthreads();
    if (tid == 0) st_flag(&flags[blk], (uint)ep);
    if (tid < 256){ while (ld_flag(&flags[tid]) < (uint)ep) __builtin_amdgcn_s_sleep(2); }
    __syncthreads();

    // ---------- phase C: chk(k) ----------
    {
      const int bn = bx<<7;
      f32x4 acc2[4][2];
      #pragma unroll
      for (int mi2=0;mi2<4;++mi2)
        #pragma unroll
        for (int ni2=0;ni2<2;++ni2) acc2[mi2][ni2] = 0.f;
      uint4 vb2[2];
      #pragma unroll
      for (int i=0;i<2;++i)
        vb2[i] = *(const uint4*)&Wchk2b[(size_t)(bn+saRow0+(i<<6))*512 + saK];
      const ushort* pc0 = hout + (size_t)(bm+saRow0)*512 + saK;
      const ushort* pc1 = pc0 + (size_t)64*512;
      for (int kt=0; kt<8; ++kt){
        u32x4 a0, a1;
        lda2_sc1(pc0 + kt*64, pc1 + kt*64, a0, a1);
        __syncthreads();
        *(u32x4*)&lsA_[saRow0*72 + saK] = a0;
        *(u32x4*)&lsA_[(saRow0+64)*72 + saK] = a1;
        #pragma unroll
        for (int i=0;i<2;++i)
          *(uint4*)&lsB_[(saRow0+(i<<6))*72 + saK] = vb2[i];
        __syncthreads();
        if (kt < 7){
          const int ko = (kt+1)<<6;
          #pragma unroll
          for (int i=0;i<2;++i)
            vb2[i] = *(const uint4*)&Wchk2b[(size_t)(bn+saRow0+(i<<6))*512 + ko + saK];
        }
        #pragma unroll
        for (int ks=0;ks<2;++ks){
          short8 af[4];
          #pragma unroll
          for (int mi2=0;mi2<4;++mi2)
            af[mi2] = *(const short8*)&lsA_[(wm + (mi2<<4) + l15)*72 + (ks<<5) + (l4<<3)];
          short8 bf2[2];
          #pragma unroll
          for (int ni2=0;ni2<2;++ni2)
            bf2[ni2] = *(const short8*)&lsB_[((wc<<5) + (ni2<<4) + l15)*72 + (ks<<5) + (l4<<3)];
          #pragma unroll
          for (int mi2=0;mi2<4;++mi2)
            #pragma unroll
            for (int ni2=0;ni2<2;++ni2)
              acc2[mi2][ni2] = __builtin_amdgcn_mfma_f32_16x16x32_bf16(af[mi2], bf2[ni2], acc2[mi2][ni2], 0,0,0);
        }
      }
      // epilogue: u = acc + chkbase ; reduce tanh(u)*cw2 over cols
      float cw2v[2];
      #pragma unroll
      for (int ni2=0;ni2<2;++ni2) cw2v[ni2] = cw2[bn + (wc<<5) + (ni2<<4) + l15];
      #pragma unroll
      for (int mi2=0;mi2<4;++mi2){
        float rs2[4];
        #pragma unroll
        for (int q=0;q<4;++q) rs2[q] = 0.f;
        #pragma unroll
        for (int q=0;q<4;++q){
          const int row = bm + wm + (mi2<<4) + (l4<<2) + q;
          #pragma unroll
          for (int ni2=0;ni2<2;++ni2){
            const int col = bn + (wc<<5) + (ni2<<4) + l15;
            const float u = acc2[mi2][ni2][q] + b2f(chkbase[(size_t)row*H_ + col]);
            rs2[q] += tanh_fast(u) * cw2v[ni2];
          }
        }
        #pragma unroll
        for (int q=0;q<4;++q){
          float v = rs2[q];
          v += __shfl_xor(v,1); v += __shfl_xor(v,2); v += __shfl_xor(v,4); v += __shfl_xor(v,8);
          if (l15==0) lred[wc][wm + (mi2<<4) + (l4<<2) + q] = v;
        }
      }
      __syncthreads();
      if (tid < 128){
        const float s = lred[0][tid] + lred[1][tid] + lred[2][tid] + lred[3][tid];
        stf_sc1(&CP[(size_t)(bm+tid)*4 + bx], s);
      }
    }
    // barrier B
    ++ep;
    __syncthreads();
    if (tid == 0) st_flag(&flags[blk], (uint)ep);
    if (tid < 256){ while (ld_flag(&flags[tid]) < (uint)ep) __builtin_amdgcn_s_sleep(2); }
    __syncthreads();
  }
}

__global__ void k_final(const float* __restrict__ acc, float* __restrict__ out)
{
  if (threadIdx.x==0){
    const float ls = acc[0], cls = acc[1], ys = acc[2];
    out[0] = (ls+cls)/ys; out[1] = ls/ys; out[2] = cls/ys;
  }
}

// ---------------- host ----------------
extern "C" void kernel_launch(void* const* d_in, const int* in_sizes, int n_in,
                              void* d_out, int out_size, void* d_ws, size_t ws_size,
                              hipStream_t stream)
{
  (void)in_sizes; (void)n_in; (void)out_size;
  const int*   x      = (const int*)d_in[0];
  const int*   akey   = (const int*)d_in[1];
  const int*   atype  = (const int*)d_in[2];
  const int*   croom  = (const int*)d_in[3];
  const float* checked= (const float*)d_in[4];
  const float* yv     = (const float*)d_in[5];
  const float* emb    = (const float*)d_in[6];
  const float* attab  = (const float*)d_in[7];
  const float* eWihF  = (const float*)d_in[8];
  const float* eWhhF  = (const float*)d_in[9];
  const float* ebihF  = (const float*)d_in[10];
  const float* ebhhF  = (const float*)d_in[11];
  const float* eWihB  = (const float*)d_in[12];
  const float* eWhhB  = (const float*)d_in[13];
  const float* ebihB  = (const float*)d_in[14];
  const float* ebhhB  = (const float*)d_in[15];
  const float* transW = (const float*)d_in[16];
  const float* transb = (const float*)d_in[17];
  const float* mergeW = (const float*)d_in[18];
  const float* mergeb = (const float*)d_in[19];
  const float* dWih   = (const float*)d_in[20];
  const float* dWhh   = (const float*)d_in[21];
  const float* dbih   = (const float*)d_in[22];
  const float* dbhh   = (const float*)d_in[23];
  const float* dW     = (const float*)d_in[24];
  const float* cW1    = (const float*)d_in[26];
  const float* cb1    = (const float*)d_in[27];
  const float* cW2    = (const float*)d_in[28];
  const float* cb2    = (const float*)d_in[29];

  char* base = (char*)d_ws;
  size_t off = 0;
  auto alloc = [&](size_t bytes)->char*{ char* p = base + off; off += (bytes + 255) & ~(size_t)255; return p; };

  float*  accv   = (float*)alloc(256);
  ushort* embxs  = (ushort*)alloc((size_t)SIN_*B_*E_*2);
  ushort* aemb   = (ushort*)alloc((size_t)Y_*E_*2);
  ushort* aembT  = (ushort*)alloc((size_t)Y_*E_*2);
  float*  avec   = (float*)alloc((size_t)Y_*32*4);
  ushort* yprev  = (ushort*)alloc((size_t)SOUT_*B_*Y_*2);
  ushort* acat   = (ushort*)alloc((size_t)SOUT_*B_*512*2);
  ushort* gi_fb  = (ushort*)alloc((size_t)2*SIN_*B_*TH_*2);
  ushort* gi_f   = gi_fb;
  ushort* gi_b   = gi_fb + (size_t)SIN_*B_*TH_;
  ushort* gibase = gi_fb;
  ushort* encout = (ushort*)alloc((size_t)B_*SIN_*1024*2);
  ushort* encoutT= (ushort*)alloc((size_t)B_*1024*SIN_*2);
  float*  hTf    = (float*)alloc((size_t)B_*H_*4);
  float*  hTb    = (float*)alloc((size_t)B_*H_*4);
  float*  h0dec  = (float*)alloc((size_t)B_*H_*4);
  ushort* esum   = (ushort*)alloc((size_t)B_*SIN_*E_*2);
  float*  scores = (float*)alloc((size_t)B_*Y_*SIN_*4);
  ushort* alpha  = (ushort*)alloc((size_t)B_*Y_*SIN_*2);
  ushort* att    = (ushort*)alloc((size_t)8192*1024*2);
  ushort* chkbase= (ushort*)alloc((size_t)8192*H_*2);
  float*  addy   = (float*)alloc((size_t)Y_*TH_*4);
  float*  addcy  = (float*)alloc((size_t)Y_*H_*4);
  float*  sproj  = (float*)alloc((size_t)SOUT_*B_*TH_*4);
  float*  wchk   = (float*)alloc((size_t)TH_*4);
  float*  dbhhrz = (float*)alloc((size_t)TH_*4);
  ushort* WihFb  = (ushort*)alloc((size_t)TH_*E_*2);
  ushort* WihBb  = (ushort*)alloc((size_t)TH_*E_*2);
  ushort* Wtrb   = (ushort*)alloc((size_t)E_*1024*2);
  ushort* Wattb  = (ushort*)alloc((size_t)TH_*1024*2);
  ushort* Wcat2b = (ushort*)alloc((size_t)TH_*512*2);
  ushort* W1attb = (ushort*)alloc((size_t)H_*1024*2);
  ushort* Wdecb  = (ushort*)alloc((size_t)TH_*512*2);
  ushort* Wchk2b = (ushort*)alloc((size_t)512*512*2);
  ushort* h2bA   = (ushort*)alloc((size_t)8192*H_*2);
  ushort* h2bB   = (ushort*)alloc((size_t)8192*H_*2);
  float*  CP     = (float*)alloc((size_t)8192*4*4);
  float*  LP0    = (float*)alloc((size_t)8192*4*4);
  float*  LP1    = (float*)alloc((size_t)8192*4*4);
  ushort* hG     = (ushort*)alloc((size_t)2*2*32*512*2);
  uint*   flags  = (uint*)alloc((size_t)256*4);
  uint*   flags2 = (uint*)alloc((size_t)256*4);

  if (off > ws_size){ k_wsfail<<<1,1,0,stream>>>((float*)d_out); return; }

  float* outp = (float*)d_out;

  k_init<<<dim3(1), dim3(64), 0, stream>>>(accv);
  k_init_enc<<<dim3(64), dim3(256), 0, stream>>>(flags, hG);
  k_ysum<<<dim3(256), dim3(256), 0, stream>>>(yv, accv);
  k_lookup<<<dim3(2048), dim3(256), 0, stream>>>(x, akey, atype, croom, yv, emb, attab,
                                                 embxs, aemb, aembT, avec, acat, yprev);
  k_convall<<<dim3(2048), dim3(256), 0, stream>>>(eWihF, eWihB, transW, dWih, cW1, dWhh,
                                                  WihFb, WihBb, Wtrb, Wattb, Wcat2b, W1attb, Wdecb, Wchk2b);
  k_prep2<<<dim3(1024), dim3(256), 0, stream>>>(avec, dWih, dbih, cW1, cb1, dbhh,
                                                addy, addcy, wchk, dbhhrz);

  // encoder input projections (bias folded in)
  gemm_nt<(GF_BIAS|GF_WBF16)><<<dim3(12,32,1), dim3(256), 0, stream>>>(
    embxs, WihFb, ebihF, nullptr, 0, nullptr, gi_f, TH_, E_, E_, E_, 0, 0L,0L,0L, nullptr);
  gemm_nt<(GF_BIAS|GF_WBF16)><<<dim3(12,32,1), dim3(256), 0, stream>>>(
    embxs, WihBb, ebihB, nullptr, 0, nullptr, gi_b, TH_, E_, E_, E_, 0, 0L,0L,0L, nullptr);

  enc_persist<<<dim3(64), dim3(256), 0, stream>>>(eWhhF, eWhhB, ebhhF, ebhhB, gi_f, gi_b,
                                                  hG, flags, encout, encoutT, hTf, hTb);

  // esum = bf16( tanh(enc_out @ trans_W^T + b) + emb )
  gemm_nt<(GF_BIAS|GF_TANH|GF_ESUM|GF_WBF16)><<<dim3(2,32,1), dim3(256), 0, stream>>>(
    encout, Wtrb, transb, nullptr, 0, nullptr, esum, E_, 1024, 1024, 1024, 0, 0L,0L,0L, embxs);

  // scores[b] = action_emb @ embsum_b^T
  gemm_nt<GF_WF32><<<dim3(1,2,32), dim3(256), 0, stream>>>(
    aemb, esum, nullptr, nullptr, 0, scores, nullptr, SIN_, E_, E_, E_, 0,
    0L, (long)SIN_*E_, (long)Y_*SIN_, nullptr);
  k_softmax<<<dim3(2048), dim3(256), 0, stream>>>(scores, alpha);

  // attention[b] = alpha_b @ enc_out_b
  gemm_nt<GF_WBF16><<<dim3(8,2,32), dim3(256), 0, stream>>>(
    alpha, encoutT, nullptr, nullptr, 0, nullptr, att, 1024, SIN_, SIN_, SIN_, 0,
    (long)Y_*SIN_, (long)1024*SIN_, (long)Y_*1024, nullptr);

  k_merge<<<dim3(32), dim3(512), 0, stream>>>(hTf, hTb, mergeW, mergeb, h0dec);

  // yemb -> acat[:,256:512]
  gemm_nt<GF_WBF16><<<dim3(2,8,1), dim3(256), 0, stream>>>(
    yprev, aembT, nullptr, nullptr, 0, nullptr, acat+256, 512, Y_, Y_, Y_, 0, 0L,0L,0L, nullptr);
  // sproj = acat @ Wcat2^T + dbhh_rz
  gemm_nt<(GF_BIAS|GF_WF32)><<<dim3(12,8,1), dim3(256), 0, stream>>>(
    acat, Wcat2b, dbhhrz, nullptr, 0, sproj, nullptr, TH_, 512, 512, 512, 0, 0L,0L,0L, nullptr);

  // gi_base = att @ W_att^T + add_y[y]   ;  chk_base = att @ W1_att^T + addc_y[y]
  gemm_nt<(GF_WBF16|GF_ADDY)><<<dim3(12,64,1), dim3(256), 0, stream>>>(
    att, Wattb, nullptr, addy, TH_, nullptr, gibase, TH_, 1024, 1024, 1024, 0, 0L,0L,0L, nullptr);
  gemm_nt<(GF_WBF16|GF_ADDY)><<<dim3(4,64,1), dim3(256), 0, stream>>>(
    att, W1attb, nullptr, addcy, H_, nullptr, chkbase, H_, 1024, 1024, 1024, 0, 0L,0L,0L, nullptr);

  k_bcast<<<dim3(1024), dim3(256), 0, stream>>>(h0dec, h2bA, flags2);

  dec_persist<<<dim3(256), dim3(512), 0, stream>>>(
    h2bA, h2bB, Wdecb, gibase, sproj, wchk, dbhh, checked, dW,
    Wchk2b, chkbase, cW2, cb2, yv, LP0, LP1, CP, flags2, accv);

  k_final<<<dim3(1), dim3(1), 0, stream>>>(accv, outp);
}